// Round 1
// baseline (3056.596 us; speedup 1.0000x reference)
//
#include <hip/hip_runtime.h>
#include <cstdint>
#include <cstddef>

// Problem constants
static constexpr int QL = 1024;   // q_len
static constexpr int KLEN = 2048; // k_len
// d_model = 1024, heads = 16, depth = 64

// ---------------------------------------------------------------------------
// Generic fp32 tiled GEMM: C[M][N] = A[M][1024] @ B[1024][N]
// gather==1: A rows come from cat(mems, inputs) per batch (2048 rows/batch)
// 64x64 tile, BK=16, 256 threads, 4x4 micro-tile per thread.
// ---------------------------------------------------------------------------
__device__ __forceinline__ const float* gemm_row_ptr(const float* A, const float* A2,
                                                     int r, int gather) {
  if (!gather) return A + (size_t)r * 1024;
  int b = r >> 11, tt = r & 2047;
  if (tt < QL) return A + ((size_t)b * QL + tt) * 1024;    // mems part
  return A2 + ((size_t)b * QL + (tt - QL)) * 1024;         // inputs part
}

__global__ __launch_bounds__(256) void gemm_f32(
    const float* __restrict__ A, const float* __restrict__ A2, int gather,
    const float* __restrict__ Bm, float* __restrict__ C, int N) {
  __shared__ __align__(16) float As[16][68];
  __shared__ __align__(16) float Bs[16][68];
  const int t = threadIdx.x;
  const int nbase = blockIdx.x * 64;
  const int mbase = blockIdx.y * 64;
  const int tm = (t & 15) * 4, tn = (t >> 4) * 4;
  const int ar = t >> 2, ak = (t & 3) * 4;
  const int bk = t >> 4, bn = (t & 15) * 4;
  const float* arow = gemm_row_ptr(A, A2, mbase + ar, gather);
  const float* bptr = Bm + (size_t)bk * N + nbase + bn;
  float c[4][4] = {};
  for (int k0 = 0; k0 < 1024; k0 += 16) {
    float4 av = *(const float4*)(arow + k0 + ak);
    float4 bv = *(const float4*)(bptr + (size_t)k0 * N);
    __syncthreads();
    As[ak + 0][ar] = av.x; As[ak + 1][ar] = av.y;
    As[ak + 2][ar] = av.z; As[ak + 3][ar] = av.w;
    *(float4*)&Bs[bk][bn] = bv;
    __syncthreads();
#pragma unroll
    for (int kk = 0; kk < 16; ++kk) {
      float4 a = *(const float4*)&As[kk][tm];
      float4 b = *(const float4*)&Bs[kk][tn];
      c[0][0] += a.x * b.x; c[0][1] += a.x * b.y; c[0][2] += a.x * b.z; c[0][3] += a.x * b.w;
      c[1][0] += a.y * b.x; c[1][1] += a.y * b.y; c[1][2] += a.y * b.z; c[1][3] += a.y * b.w;
      c[2][0] += a.z * b.x; c[2][1] += a.z * b.y; c[2][2] += a.z * b.z; c[2][3] += a.z * b.w;
      c[3][0] += a.w * b.x; c[3][1] += a.w * b.y; c[3][2] += a.w * b.z; c[3][3] += a.w * b.w;
    }
  }
#pragma unroll
  for (int i = 0; i < 4; ++i) {
    float4 v = make_float4(c[i][0], c[i][1], c[i][2], c[i][3]);
    *(float4*)(C + (size_t)(mbase + tm + i) * N + nbase + tn) = v;
  }
}

// ---------------------------------------------------------------------------
// cdelta[h][jr] = sum_d (r_r_bias[h][d] - r_w_bias[h][d]) * rbuf[jr][h*64+d]
// ---------------------------------------------------------------------------
__global__ __launch_bounds__(256) void cdelta_kernel(
    const float* __restrict__ rbuf, const float* __restrict__ rwb,
    const float* __restrict__ rrb, float* __restrict__ cd) {
  int idx = blockIdx.x * 256 + threadIdx.x;  // 32768 total
  int jr = idx >> 4, h = idx & 15;
  const float* rp = rbuf + (size_t)jr * 1024 + h * 64;
  const float* a = rrb + h * 64;
  const float* b = rwb + h * 64;
  float s = 0.f;
#pragma unroll 8
  for (int d = 0; d < 64; ++d) s += (a[d] - b[d]) * rp[d];
  cd[h * 2048 + jr] = s;
}

// ---------------------------------------------------------------------------
// Flash-style attention with relative-position term.
//   score[i][j] = ( qw_i·k_j + qw_i·r_{j-i+1023} + cdelta[h][j-i+1023] ) / 8
//   qw = q + r_w_bias ;  mask: j <= i + 1024
// Block: (q-tile of 32) x (head) x (batch); K-tiles of 32; r window 63 rows.
// ---------------------------------------------------------------------------
__global__ __launch_bounds__(256) void attn_kernel(
    const float* __restrict__ qkv, const float* __restrict__ rbuf,
    const float* __restrict__ cdelta, const float* __restrict__ rwb,
    float* __restrict__ av) {
  const int qt = blockIdx.x, h = blockIdx.y, b = blockIdx.z;
  const int qbase = qt * 32;
  __shared__ __align__(16) float qw[32][68];    // [q][d]
  __shared__ __align__(16) float ks_t[64][68];  // [d][j]  (transposed)
  __shared__ __align__(16) float rs_t[64][68];  // [d][rl] (transposed, 63 cols used)
  __shared__ __align__(16) float vs[32][68];    // [j][d]
  __shared__ __align__(16) float sc[32][36];    // scores [q][j]
  __shared__ float cd[64];
  const int t = threadIdx.x;

  // stage qw = q + r_w_bias (once)
  {
    int qr = t >> 3, db = (t & 7) * 8;
    const float* src = qkv + ((size_t)b * 2048 + 1024 + qbase + qr) * 3072 + h * 64 + db;
    const float* wb = rwb + h * 64 + db;
    float4 s0 = *(const float4*)src;
    float4 s1 = *(const float4*)(src + 4);
    float4 w0 = *(const float4*)wb;
    float4 w1 = *(const float4*)(wb + 4);
    qw[qr][db + 0] = s0.x + w0.x; qw[qr][db + 1] = s0.y + w0.y;
    qw[qr][db + 2] = s0.z + w0.z; qw[qr][db + 3] = s0.w + w0.w;
    qw[qr][db + 4] = s1.x + w1.x; qw[qr][db + 5] = s1.y + w1.y;
    qw[qr][db + 6] = s1.z + w1.z; qw[qr][db + 7] = s1.w + w1.w;
  }

  const int p1_qr = t >> 3, p1_jlb = (t & 7) * 4;
  const int p1_i = qbase + p1_qr;
  const int p1_rlb = p1_jlb + 31 - p1_qr;  // r-window column base, in [0,59]
  const int p2_qr = t & 31, p2_d0 = (t >> 5) * 8;

  float m = -1e30f, l = 0.f;
  float acc[8] = {0.f,0.f,0.f,0.f,0.f,0.f,0.f,0.f};

  const int ktiles = qbase / 32 + 33;  // covers j in [0, qbase+1056)
  for (int kt = 0; kt < ktiles; ++kt) {
    const int kbase = kt * 32;
    const int rbase = kbase - qbase + 992;  // global r row of window col 0 (>=0 always)
    __syncthreads();
    // ---- stage k, v, r-window, cdelta-window ----
    {
      int jl = t >> 3, db = (t & 7) * 8;
      const float* kp = qkv + ((size_t)b * 2048 + kbase + jl) * 3072 + (16 + h) * 64 + db;
      const float* vp = kp + 1024;  // v head offset (32+h)*64
      float4 k0 = *(const float4*)kp;       float4 k1 = *(const float4*)(kp + 4);
      float4 v0 = *(const float4*)vp;       float4 v1 = *(const float4*)(vp + 4);
      ks_t[db + 0][jl] = k0.x; ks_t[db + 1][jl] = k0.y;
      ks_t[db + 2][jl] = k0.z; ks_t[db + 3][jl] = k0.w;
      ks_t[db + 4][jl] = k1.x; ks_t[db + 5][jl] = k1.y;
      ks_t[db + 6][jl] = k1.z; ks_t[db + 7][jl] = k1.w;
      *(float4*)&vs[jl][db] = v0;
      *(float4*)&vs[jl][db + 4] = v1;
      if (t < 252) {  // 63 rows x 4 chunks of 16 floats
        int rl = t >> 2, db2 = (t & 3) * 16;
        int rj = rbase + rl; if (rj > 2047) rj = 2047;  // clamped rows feed masked cells only
        const float* rp = rbuf + (size_t)rj * 1024 + h * 64 + db2;
#pragma unroll
        for (int i2 = 0; i2 < 16; i2 += 4) {
          float4 rv = *(const float4*)(rp + i2);
          rs_t[db2 + i2 + 0][rl] = rv.x; rs_t[db2 + i2 + 1][rl] = rv.y;
          rs_t[db2 + i2 + 2][rl] = rv.z; rs_t[db2 + i2 + 3][rl] = rv.w;
        }
      }
      if (t < 63) {
        int rj = rbase + t; if (rj > 2047) rj = 2047;
        cd[t] = cdelta[h * 2048 + rj];
      }
    }
    __syncthreads();
    // ---- phase 1: scores ----
    {
      float ac[4] = {0.f,0.f,0.f,0.f}, bd[4] = {0.f,0.f,0.f,0.f};
#pragma unroll
      for (int d4 = 0; d4 < 64; d4 += 4) {
        float4 qv = *(const float4*)&qw[p1_qr][d4];
        float qd[4] = {qv.x, qv.y, qv.z, qv.w};
#pragma unroll
        for (int i2 = 0; i2 < 4; ++i2) {
          float4 kv = *(const float4*)&ks_t[d4 + i2][p1_jlb];
          const float* rrow = &rs_t[d4 + i2][p1_rlb];
          float q = qd[i2];
          ac[0] += q * kv.x; ac[1] += q * kv.y; ac[2] += q * kv.z; ac[3] += q * kv.w;
          bd[0] += q * rrow[0]; bd[1] += q * rrow[1];
          bd[2] += q * rrow[2]; bd[3] += q * rrow[3];
        }
      }
      const int lim = p1_i + 1024;
#pragma unroll
      for (int jj = 0; jj < 4; ++jj) {
        float s = (ac[jj] + bd[jj] + cd[p1_rlb + jj]) * 0.125f;
        if (kbase + p1_jlb + jj > lim) s = -1e30f;
        sc[p1_qr][p1_jlb + jj] = s;
      }
    }
    __syncthreads();
    // ---- phase 2: online softmax + PV ----
    {
      float s[32];
#pragma unroll
      for (int j4 = 0; j4 < 32; j4 += 4)
        *(float4*)&s[j4] = *(const float4*)&sc[p2_qr][j4];
      float mt = s[0];
#pragma unroll
      for (int j = 1; j < 32; ++j) mt = fmaxf(mt, s[j]);
      float mn = fmaxf(m, mt);
      float alpha = __expf(m - mn);
      l *= alpha;
#pragma unroll
      for (int dd = 0; dd < 8; ++dd) acc[dd] *= alpha;
#pragma unroll
      for (int j = 0; j < 32; ++j) {
        float p = __expf(s[j] - mn);
        l += p;
        float4 v0 = *(const float4*)&vs[j][p2_d0];
        float4 v1 = *(const float4*)&vs[j][p2_d0 + 4];
        acc[0] += p * v0.x; acc[1] += p * v0.y; acc[2] += p * v0.z; acc[3] += p * v0.w;
        acc[4] += p * v1.x; acc[5] += p * v1.y; acc[6] += p * v1.z; acc[7] += p * v1.w;
      }
      m = mn;
    }
  }
  float inv = 1.f / l;
  float* op = av + ((size_t)b * 1024 + qbase + p2_qr) * 1024 + h * 64 + p2_d0;
  *(float4*)op       = make_float4(acc[0]*inv, acc[1]*inv, acc[2]*inv, acc[3]*inv);
  *(float4*)(op + 4) = make_float4(acc[4]*inv, acc[5]*inv, acc[6]*inv, acc[7]*inv);
}

// ---------------------------------------------------------------------------
extern "C" void kernel_launch(void* const* d_in, const int* in_sizes, int n_in,
                              void* d_out, int out_size, void* d_ws, size_t ws_size,
                              hipStream_t stream) {
  const float* inputs  = (const float*)d_in[0];
  const float* pos_emb = (const float*)d_in[1];
  const float* rwb     = (const float*)d_in[2];
  const float* rrb     = (const float*)d_in[3];
  const float* mems    = (const float*)d_in[4];
  const float* W_w     = (const float*)d_in[5];
  const float* W_r     = (const float*)d_in[6];
  const float* W_o     = (const float*)d_in[7];
  float* out = (float*)d_out;
  float* ws  = (float*)d_ws;

  float* qkv    = ws;                                   // 4*2048*3072
  float* rbuf   = qkv  + (size_t)4 * 2048 * 3072;       // 2048*1024
  float* cdelta = rbuf + (size_t)2048 * 1024;           // 16*2048
  float* av     = cdelta + (size_t)16 * 2048;           // 4*1024*1024

  // 1) qkv = cat(mems, inputs) @ W_w   (M=8192, N=3072)
  gemm_f32<<<dim3(3072 / 64, 8192 / 64), 256, 0, stream>>>(mems, inputs, 1, W_w, qkv, 3072);
  // 2) r = pos_emb @ W_r               (M=2048, N=1024)
  gemm_f32<<<dim3(1024 / 64, 2048 / 64), 256, 0, stream>>>(pos_emb, nullptr, 0, W_r, rbuf, 1024);
  // 3) cdelta
  cdelta_kernel<<<128, 256, 0, stream>>>(rbuf, rwb, rrb, cdelta);
  // 4) attention
  attn_kernel<<<dim3(32, 16, 4), 256, 0, stream>>>(qkv, rbuf, cdelta, rwb, av);
  // 5) out = attn_vec @ W_o            (M=4096, N=1024)
  gemm_f32<<<dim3(1024 / 64, 4096 / 64), 256, 0, stream>>>(av, nullptr, 0, W_o, out, 1024);
}

// Round 2
// 1177.981 us; speedup vs baseline: 2.5948x; 2.5948x over previous
//
#include <hip/hip_runtime.h>
#include <cstdint>
#include <cstddef>

static constexpr int QL = 1024;   // q_len
// k_len = 2048, d_model = 1024, heads = 16, depth = 64

typedef _Float16 half8 __attribute__((ext_vector_type(8)));
typedef _Float16 half4 __attribute__((ext_vector_type(4)));
typedef float f32x4 __attribute__((ext_vector_type(4)));

// ---------------------------------------------------------------------------
// Generic fp32 tiled GEMM: C[M][N] = A[M][1024] @ B[1024][N]   (unchanged)
// ---------------------------------------------------------------------------
__device__ __forceinline__ const float* gemm_row_ptr(const float* A, const float* A2,
                                                     int r, int gather) {
  if (!gather) return A + (size_t)r * 1024;
  int b = r >> 11, tt = r & 2047;
  if (tt < QL) return A + ((size_t)b * QL + tt) * 1024;    // mems part
  return A2 + ((size_t)b * QL + (tt - QL)) * 1024;         // inputs part
}

__global__ __launch_bounds__(256) void gemm_f32(
    const float* __restrict__ A, const float* __restrict__ A2, int gather,
    const float* __restrict__ Bm, float* __restrict__ C, int N) {
  __shared__ __align__(16) float As[16][68];
  __shared__ __align__(16) float Bs[16][68];
  const int t = threadIdx.x;
  const int nbase = blockIdx.x * 64;
  const int mbase = blockIdx.y * 64;
  const int tm = (t & 15) * 4, tn = (t >> 4) * 4;
  const int ar = t >> 2, ak = (t & 3) * 4;
  const int bk = t >> 4, bn = (t & 15) * 4;
  const float* arow = gemm_row_ptr(A, A2, mbase + ar, gather);
  const float* bptr = Bm + (size_t)bk * N + nbase + bn;
  float c[4][4] = {};
  for (int k0 = 0; k0 < 1024; k0 += 16) {
    float4 av = *(const float4*)(arow + k0 + ak);
    float4 bv = *(const float4*)(bptr + (size_t)k0 * N);
    __syncthreads();
    As[ak + 0][ar] = av.x; As[ak + 1][ar] = av.y;
    As[ak + 2][ar] = av.z; As[ak + 3][ar] = av.w;
    *(float4*)&Bs[bk][bn] = bv;
    __syncthreads();
#pragma unroll
    for (int kk = 0; kk < 16; ++kk) {
      float4 a = *(const float4*)&As[kk][tm];
      float4 b = *(const float4*)&Bs[kk][tn];
      c[0][0] += a.x * b.x; c[0][1] += a.x * b.y; c[0][2] += a.x * b.z; c[0][3] += a.x * b.w;
      c[1][0] += a.y * b.x; c[1][1] += a.y * b.y; c[1][2] += a.y * b.z; c[1][3] += a.y * b.w;
      c[2][0] += a.z * b.x; c[2][1] += a.z * b.y; c[2][2] += a.z * b.z; c[2][3] += a.z * b.w;
      c[3][0] += a.w * b.x; c[3][1] += a.w * b.y; c[3][2] += a.w * b.z; c[3][3] += a.w * b.w;
    }
  }
#pragma unroll
  for (int i = 0; i < 4; ++i) {
    float4 v = make_float4(c[i][0], c[i][1], c[i][2], c[i][3]);
    *(float4*)(C + (size_t)(mbase + tm + i) * N + nbase + tn) = v;
  }
}

// ---------------------------------------------------------------------------
// cdelta[h][jr] = sum_d (r_r_bias[h][d] - r_w_bias[h][d]) * rbuf[jr][h*64+d]
// ---------------------------------------------------------------------------
__global__ __launch_bounds__(256) void cdelta_kernel(
    const float* __restrict__ rbuf, const float* __restrict__ rwb,
    const float* __restrict__ rrb, float* __restrict__ cd) {
  int idx = blockIdx.x * 256 + threadIdx.x;  // 32768 total
  int jr = idx >> 4, h = idx & 15;
  const float* rp = rbuf + (size_t)jr * 1024 + h * 64;
  const float* a = rrb + h * 64;
  const float* b = rwb + h * 64;
  float s = 0.f;
#pragma unroll 8
  for (int d = 0; d < 64; ++d) s += (a[d] - b[d]) * rp[d];
  cd[h * 2048 + jr] = s;
}

// ---------------------------------------------------------------------------
// fp16 conversion pre-passes (head-major packed layouts for the MFMA attn)
// qw16[b][h][q][d] = fp16(q + r_w_bias) ; k16[b][h][j][d] ; vt16[b][h][d][j]
// r16[h][jr][d]
// ---------------------------------------------------------------------------
__global__ __launch_bounds__(256) void convert_qk(
    const float* __restrict__ qkv, const float* __restrict__ rwb,
    _Float16* __restrict__ qw16, _Float16* __restrict__ k16) {
  const int bid = blockIdx.x;            // b*2048 + trow
  const int b = bid >> 11, trow = bid & 2047;
  const int c = threadIdx.x * 4;         // 0..1023
  const int h = c >> 6, d = c & 63;
  // K part (cols 1024..2047)
  float4 kv = *(const float4*)(qkv + (size_t)bid * 3072 + 1024 + c);
  half4 ko = { (_Float16)kv.x, (_Float16)kv.y, (_Float16)kv.z, (_Float16)kv.w };
  *(half4*)(k16 + (((size_t)(b * 16 + h)) * 2048 + trow) * 64 + d) = ko;
  // QW part (only current-segment rows)
  if (trow >= 1024) {
    int q = trow - 1024;
    float4 qv = *(const float4*)(qkv + (size_t)bid * 3072 + c);
    float4 wv = *(const float4*)(rwb + c);
    half4 qo = { (_Float16)(qv.x + wv.x), (_Float16)(qv.y + wv.y),
                 (_Float16)(qv.z + wv.z), (_Float16)(qv.w + wv.w) };
    *(half4*)(qw16 + (((size_t)(b * 16 + h)) * 1024 + q) * 64 + d) = qo;
  }
}

__global__ __launch_bounds__(256) void convert_r(
    const float* __restrict__ rbuf, _Float16* __restrict__ r16) {
  const int jr = blockIdx.x;             // 0..2047
  const int c = threadIdx.x * 4;
  const int h = c >> 6, d = c & 63;
  float4 rv = *(const float4*)(rbuf + (size_t)jr * 1024 + c);
  half4 ro = { (_Float16)rv.x, (_Float16)rv.y, (_Float16)rv.z, (_Float16)rv.w };
  *(half4*)(r16 + ((size_t)h * 2048 + jr) * 64 + d) = ro;
}

__global__ __launch_bounds__(256) void convert_vt(
    const float* __restrict__ qkv, _Float16* __restrict__ vt16) {
  __shared__ _Float16 T[64][40];
  const int bid = blockIdx.x;            // (b*16+h)*64 + jt
  const int jt = bid & 63, h = (bid >> 6) & 15, b = bid >> 10;
  const int t = threadIdx.x;
  {
    int j = t >> 3, d0 = (t & 7) * 8;
    const float* src = qkv + ((size_t)(b * 2048) + jt * 32 + j) * 3072 + 2048 + h * 64 + d0;
    float4 v0 = *(const float4*)src;
    float4 v1 = *(const float4*)(src + 4);
    T[d0 + 0][j] = (_Float16)v0.x; T[d0 + 1][j] = (_Float16)v0.y;
    T[d0 + 2][j] = (_Float16)v0.z; T[d0 + 3][j] = (_Float16)v0.w;
    T[d0 + 4][j] = (_Float16)v1.x; T[d0 + 5][j] = (_Float16)v1.y;
    T[d0 + 6][j] = (_Float16)v1.z; T[d0 + 7][j] = (_Float16)v1.w;
  }
  __syncthreads();
  {
    int d = t >> 2, j0 = (t & 3) * 8;
    half8 v = *(const half8*)&T[d][j0];
    *(half8*)(vt16 + (((size_t)(b * 16 + h)) * 64 + d) * 2048 + jt * 32 + j0) = v;
  }
}

// ---------------------------------------------------------------------------
// MFMA flash attention. Block = (qtile 64, head, batch); 4 waves, each owns
// 16 q-rows (softmax rows never cross waves). K-tile = 32.
//   score[i][j] = ( qw_i.k_j + T + cdelta[h][j-i+1023] ) / 8 ; mask j<=i+1024
//   T = qw_i . r_{j-i+1023}   computed as per-wave 48-col window GEMM,
//   diagonal extracted from C-frags via __shfl (row-dependent rotate).
// ---------------------------------------------------------------------------
__global__ __launch_bounds__(256) void attn_mfma(
    const _Float16* __restrict__ qw16, const _Float16* __restrict__ k16,
    const _Float16* __restrict__ vt16, const _Float16* __restrict__ r16,
    const float* __restrict__ cdelta, float* __restrict__ av) {
  __shared__ _Float16 qw_s[64][72];
  __shared__ _Float16 k_s[32][72];
  __shared__ _Float16 r_s[96][72];
  __shared__ _Float16 vt_s[64][40];
  __shared__ _Float16 P_s[64][40];
  __shared__ float cdw_s[96];

  const int qt = blockIdx.x, h = blockIdx.y, b = blockIdx.z;
  const int qbase = qt * 64;
  const int bh = b * 16 + h;
  const int t = threadIdx.x;
  const int lane = t & 63, w = t >> 6;
  const int ln = lane & 15, g = lane >> 4;

  // stage qw (whole block's 64 rows, once)
#pragma unroll
  for (int i = 0; i < 2; ++i) {
    int idx = t + i * 256;              // 0..511
    int row = idx >> 3, d0 = (idx & 7) * 8;
    *(half8*)&qw_s[row][d0] =
        *(const half8*)(qw16 + ((size_t)bh * 1024 + qbase + row) * 64 + d0);
  }

  f32x4 O[4] = {};
  float mold[4] = {-1e30f, -1e30f, -1e30f, -1e30f};
  float llane[4] = {0.f, 0.f, 0.f, 0.f};
  const int rb = 48 - 16 * w;           // wave window base inside r_s

  const int ktiles = 2 * qt + 34;
  for (int kt = 0; kt < ktiles; ++kt) {
    const int kbase = kt * 32;
    const int R = kbase - qbase + 960;  // global r row of r_s row 0 (>=0)
    const int climit = qbase + 16 * w + 1039 - kbase;
    __syncthreads();
    { // ---- stage K, VT, R-window, cdelta-window ----
      int j = t >> 3, d0 = (t & 7) * 8;
      *(half8*)&k_s[j][d0] =
          *(const half8*)(k16 + ((size_t)bh * 2048 + kbase + j) * 64 + d0);
      int dv = t >> 2, jv = (t & 3) * 8;
      *(half8*)&vt_s[dv][jv] =
          *(const half8*)(vt16 + ((size_t)bh * 64 + dv) * 2048 + kbase + jv);
#pragma unroll
      for (int i = 0; i < 3; ++i) {
        int idx = t + i * 256;          // 0..767
        int row = idx >> 3, c8 = (idx & 7) * 8;
        int rr = R + row; rr = rr > 2047 ? 2047 : rr;
        *(half8*)&r_s[row][c8] =
            *(const half8*)(r16 + ((size_t)h * 2048 + rr) * 64 + c8);
      }
      if (t < 96) {
        int rr = R + t; rr = rr > 2047 ? 2047 : rr;
        cdw_s[t] = cdelta[h * 2048 + rr];
      }
    }
    __syncthreads();

    // ---- A fragments (wave's 16 q-rows) ----
    const _Float16* qrow = &qw_s[16 * w + ln][0];
    half8 aq0 = *(const half8*)(qrow + g * 8);
    half8 aq1 = *(const half8*)(qrow + 32 + g * 8);

    // ---- QK^T : 2 j-tiles ----
    f32x4 Sf[2];
#pragma unroll
    for (int jt = 0; jt < 2; ++jt) {
      const _Float16* kr = &k_s[jt * 16 + ln][0];
      half8 b0 = *(const half8*)(kr + g * 8);
      half8 b1 = *(const half8*)(kr + 32 + g * 8);
      f32x4 z = {0.f, 0.f, 0.f, 0.f};
      z = __builtin_amdgcn_mfma_f32_16x16x32_f16(aq0, b0, z, 0, 0, 0);
      z = __builtin_amdgcn_mfma_f32_16x16x32_f16(aq1, b1, z, 0, 0, 0);
      Sf[jt] = z;
    }
    // ---- window product T : 3 col-tiles of 16 ----
    f32x4 Tf[3];
#pragma unroll
    for (int ft = 0; ft < 3; ++ft) {
      const _Float16* rr_ = &r_s[rb + ft * 16 + ln][0];
      half8 b0 = *(const half8*)(rr_ + g * 8);
      half8 b1 = *(const half8*)(rr_ + 32 + g * 8);
      f32x4 z = {0.f, 0.f, 0.f, 0.f};
      z = __builtin_amdgcn_mfma_f32_16x16x32_f16(aq0, b0, z, 0, 0, 0);
      z = __builtin_amdgcn_mfma_f32_16x16x32_f16(aq1, b1, z, 0, 0, 0);
      Tf[ft] = z;
    }

    // ---- assemble S: shift-gather T diagonal, add cdelta, scale, mask ----
    float sv[2][4];
#pragma unroll
    for (int jt = 0; jt < 2; ++jt) {
#pragma unroll
      for (int r = 0; r < 4; ++r) {
        int cw = jt * 16 + ln + 15 - 4 * g - r;     // wave window col, 0..46
        int src = (lane & 48) | (cw & 15);
        float t0 = __shfl(Tf[0][r], src, 64);
        float t1 = __shfl(Tf[1][r], src, 64);
        float t2 = __shfl(Tf[2][r], src, 64);
        float tv = (cw < 16) ? t0 : ((cw < 32) ? t1 : t2);
        float s = (Sf[jt][r] + tv + cdw_s[cw + rb]) * 0.125f;
        sv[jt][r] = (cw > climit) ? -1e30f : s;
      }
    }
    // ---- online softmax (rows live inside 16-lane groups) ----
    float alpha[4];
#pragma unroll
    for (int r = 0; r < 4; ++r) {
      float mx = fmaxf(sv[0][r], sv[1][r]);
      mx = fmaxf(mx, __shfl_xor(mx, 1, 64));
      mx = fmaxf(mx, __shfl_xor(mx, 2, 64));
      mx = fmaxf(mx, __shfl_xor(mx, 4, 64));
      mx = fmaxf(mx, __shfl_xor(mx, 8, 64));
      float mn = fmaxf(mold[r], mx);
      float al = __expf(mold[r] - mn);
      mold[r] = mn;
      float p0 = __expf(sv[0][r] - mn);
      float p1 = __expf(sv[1][r] - mn);
      llane[r] = llane[r] * al + p0 + p1;
      int prow = w * 16 + 4 * g + r;
      P_s[prow][ln] = (_Float16)p0;
      P_s[prow][16 + ln] = (_Float16)p1;
      alpha[r] = al;
    }
#pragma unroll
    for (int dt = 0; dt < 4; ++dt)
#pragma unroll
      for (int r = 0; r < 4; ++r) O[dt][r] *= alpha[r];

    __builtin_amdgcn_s_waitcnt(0);  // drain P_s writes (wave-local, no barrier)

    // ---- PV: A = P (C->A via LDS patch), B = V^T ----
    half8 pA = *(const half8*)&P_s[w * 16 + ln][g * 8];
#pragma unroll
    for (int dt = 0; dt < 4; ++dt) {
      half8 bv = *(const half8*)&vt_s[dt * 16 + ln][g * 8];
      O[dt] = __builtin_amdgcn_mfma_f32_16x16x32_f16(pA, bv, O[dt], 0, 0, 0);
    }
  }

  // ---- epilogue: reduce l across the 16-lane row group, normalize, store ----
#pragma unroll
  for (int r = 0; r < 4; ++r) {
    float ls = llane[r];
    ls += __shfl_xor(ls, 1, 64);
    ls += __shfl_xor(ls, 2, 64);
    ls += __shfl_xor(ls, 4, 64);
    ls += __shfl_xor(ls, 8, 64);
    float inv = 1.f / ls;
    int qrow = qbase + 16 * w + 4 * g + r;
    float* op = av + ((size_t)b * 1024 + qrow) * 1024 + h * 64 + ln;
#pragma unroll
    for (int dt = 0; dt < 4; ++dt) op[dt * 16] = O[dt][r] * inv;
  }
}

// ---------------------------------------------------------------------------
extern "C" void kernel_launch(void* const* d_in, const int* in_sizes, int n_in,
                              void* d_out, int out_size, void* d_ws, size_t ws_size,
                              hipStream_t stream) {
  const float* inputs  = (const float*)d_in[0];
  const float* pos_emb = (const float*)d_in[1];
  const float* rwb     = (const float*)d_in[2];
  const float* rrb     = (const float*)d_in[3];
  const float* mems    = (const float*)d_in[4];
  const float* W_w     = (const float*)d_in[5];
  const float* W_r     = (const float*)d_in[6];
  const float* W_o     = (const float*)d_in[7];
  float* out = (float*)d_out;
  float* ws  = (float*)d_ws;

  float* qkv    = ws;                                   // 4*2048*3072 f32
  float* rbuf   = qkv  + (size_t)4 * 2048 * 3072;       // 2048*1024 f32
  float* cdelta = rbuf + (size_t)2048 * 1024;           // 16*2048 f32
  float* av     = cdelta + (size_t)16 * 2048;           // 4*1024*1024 f32
  _Float16* qw16 = (_Float16*)(av + (size_t)4 * 1024 * 1024); // 4*16*1024*64
  _Float16* k16  = qw16 + (size_t)4 * 16 * 1024 * 64;         // 4*16*2048*64
  _Float16* vt16 = k16  + (size_t)4 * 16 * 2048 * 64;         // 4*16*64*2048
  _Float16* r16  = vt16 + (size_t)4 * 16 * 64 * 2048;         // 16*2048*64

  // 1) qkv = cat(mems, inputs) @ W_w   (M=8192, N=3072)
  gemm_f32<<<dim3(3072 / 64, 8192 / 64), 256, 0, stream>>>(mems, inputs, 1, W_w, qkv, 3072);
  // 2) r = pos_emb @ W_r               (M=2048, N=1024)
  gemm_f32<<<dim3(1024 / 64, 2048 / 64), 256, 0, stream>>>(pos_emb, nullptr, 0, W_r, rbuf, 1024);
  // 3) cdelta
  cdelta_kernel<<<128, 256, 0, stream>>>(rbuf, rwb, rrb, cdelta);
  // 4) fp16 packing
  convert_qk<<<8192, 256, 0, stream>>>(qkv, rwb, qw16, k16);
  convert_r<<<2048, 256, 0, stream>>>(rbuf, r16);
  convert_vt<<<4096, 256, 0, stream>>>(qkv, vt16);
  // 5) MFMA flash attention
  attn_mfma<<<dim3(16, 16, 4), 256, 0, stream>>>(qw16, k16, vt16, r16, cdelta, av);
  // 6) out = attn_vec @ W_o            (M=4096, N=1024)
  gemm_f32<<<dim3(1024 / 64, 4096 / 64), 256, 0, stream>>>(av, nullptr, 0, W_o, out, 1024);
}

// Round 3
// 656.170 us; speedup vs baseline: 4.6582x; 1.7952x over previous
//
#include <hip/hip_runtime.h>
#include <cstdint>
#include <cstddef>

static constexpr int QL = 1024;   // q_len
// k_len = 2048, d_model = 1024, heads = 16, depth = 64

typedef _Float16 half8 __attribute__((ext_vector_type(8)));
typedef _Float16 half4 __attribute__((ext_vector_type(4)));
typedef float f32x4 __attribute__((ext_vector_type(4)));

// ---------------------------------------------------------------------------
// gather: A rows come from cat(mems, inputs) per batch (2048 rows/batch)
// ---------------------------------------------------------------------------
__device__ __forceinline__ const float* gemm_row_ptr(const float* A, const float* A2,
                                                     int r, int gather) {
  if (!gather) return A + (size_t)r * 1024;
  int b = r >> 11, tt = r & 2047;
  if (tt < QL) return A + ((size_t)b * QL + tt) * 1024;    // mems part
  return A2 + ((size_t)b * QL + (tt - QL)) * 1024;         // inputs part
}

// ---------------------------------------------------------------------------
// Pre-pass: W[1024][N] -> Wt[N][2048] fp16, rows = [k-tile 0: hi32|lo32][...]
// i.e. Wt[n][kt*64 + p] = hi(W[kt*32+p][n]), Wt[n][kt*64+32+p] = lo.
// ---------------------------------------------------------------------------
__global__ __launch_bounds__(256) void split_w(
    const float* __restrict__ W, _Float16* __restrict__ Wt, int N) {
  __shared__ float T[64][65];
  const int nb = blockIdx.x * 64, kb = blockIdx.y * 64;
  const int t = threadIdx.x;
  {
    int row = t >> 2, c0 = (t & 3) * 16;
    const float* src = W + (size_t)(kb + row) * N + nb + c0;
#pragma unroll
    for (int c = 0; c < 16; c += 4) {
      float4 v = *(const float4*)(src + c);
      T[row][c0 + c + 0] = v.x; T[row][c0 + c + 1] = v.y;
      T[row][c0 + c + 2] = v.z; T[row][c0 + c + 3] = v.w;
    }
  }
  __syncthreads();
  {
    int nrow = t >> 2, ks = (t & 3) * 16;
    half8 hi0, hi1, lo0, lo1;
#pragma unroll
    for (int c = 0; c < 16; ++c) {
      float f = T[ks + c][nrow];
      _Float16 h = (_Float16)f;
      _Float16 l = (_Float16)(f - (float)h);
      if (c < 8) { hi0[c] = h; lo0[c] = l; } else { hi1[c - 8] = h; lo1[c - 8] = l; }
    }
    int kglob = kb + ks;
    int kt = kglob >> 5, pos = kglob & 31;
    _Float16* dst = Wt + (size_t)(nb + nrow) * 2048 + kt * 64 + pos;
    *(half8*)dst = hi0; *(half8*)(dst + 8) = hi1;
    *(half8*)(dst + 32) = lo0; *(half8*)(dst + 40) = lo1;
  }
}

// ---------------------------------------------------------------------------
// Split-fp16 MFMA GEMM: C[M][N] = A[M][1024] @ W[1024][N], fp32-accurate via
// Ahi@Whi + Ahi@Wlo + Alo@Whi. A read fp32 (split inline); W from split_w.
// 128x128 tile, BK=32, 4 waves each 64x64 (4x4 frags of 16x16x32).
// ---------------------------------------------------------------------------
__global__ __launch_bounds__(256) void gemm_mfma_split(
    const float* __restrict__ A, const float* __restrict__ A2, int gather,
    const _Float16* __restrict__ Bt, float* __restrict__ C, int N) {
  __shared__ _Float16 As[128][72];   // [m][k]hi, [m][32+k]lo
  __shared__ _Float16 Bs[128][72];   // [n][k]hi, [n][32+k]lo
  const int t = threadIdx.x;
  const int nbase = blockIdx.x * 128, mbase = blockIdx.y * 128;
  const int lane = t & 63, w = t >> 6;
  const int ln = lane & 15, g = lane >> 4;
  const int wm = (w & 1) * 64, wn = (w >> 1) * 64;
  const int ar = t >> 1, asg = (t & 1) * 16;   // A: row, k-seg base
  const int br = t >> 1, bsg = (t & 1) * 32;   // B: row, fp16-seg base
  const float* arow = gemm_row_ptr(A, A2, mbase + ar, gather) + asg;
  const _Float16* brow = Bt + (size_t)(nbase + br) * 2048 + bsg;

  f32x4 acc[4][4] = {};
  for (int kt = 0; kt < 32; ++kt) {
    // global loads (A fp32 16 elems, B fp16 32 elems)
    float4 av0 = *(const float4*)(arow + kt * 32 + 0);
    float4 av1 = *(const float4*)(arow + kt * 32 + 4);
    float4 av2 = *(const float4*)(arow + kt * 32 + 8);
    float4 av3 = *(const float4*)(arow + kt * 32 + 12);
    half8 bv0 = *(const half8*)(brow + kt * 64 + 0);
    half8 bv1 = *(const half8*)(brow + kt * 64 + 8);
    half8 bv2 = *(const half8*)(brow + kt * 64 + 16);
    half8 bv3 = *(const half8*)(brow + kt * 64 + 24);
    // inline split of A
    half8 ahi0, ahi1, alo0, alo1;
    float fa[16] = {av0.x, av0.y, av0.z, av0.w, av1.x, av1.y, av1.z, av1.w,
                    av2.x, av2.y, av2.z, av2.w, av3.x, av3.y, av3.z, av3.w};
#pragma unroll
    for (int c = 0; c < 16; ++c) {
      _Float16 h = (_Float16)fa[c];
      _Float16 l = (_Float16)(fa[c] - (float)h);
      if (c < 8) { ahi0[c] = h; alo0[c] = l; } else { ahi1[c - 8] = h; alo1[c - 8] = l; }
    }
    __syncthreads();
    *(half8*)&As[ar][asg] = ahi0;      *(half8*)&As[ar][asg + 8] = ahi1;
    *(half8*)&As[ar][32 + asg] = alo0; *(half8*)&As[ar][32 + asg + 8] = alo1;
    *(half8*)&Bs[br][bsg + 0] = bv0;   *(half8*)&Bs[br][bsg + 8] = bv1;
    *(half8*)&Bs[br][bsg + 16] = bv2;  *(half8*)&Bs[br][bsg + 24] = bv3;
    __syncthreads();
    half8 ah[4], al[4], bh[4], bl[4];
#pragma unroll
    for (int i = 0; i < 4; ++i) {
      ah[i] = *(const half8*)&As[wm + i * 16 + ln][g * 8];
      al[i] = *(const half8*)&As[wm + i * 16 + ln][32 + g * 8];
    }
#pragma unroll
    for (int j = 0; j < 4; ++j) {
      bh[j] = *(const half8*)&Bs[wn + j * 16 + ln][g * 8];
      bl[j] = *(const half8*)&Bs[wn + j * 16 + ln][32 + g * 8];
    }
#pragma unroll
    for (int i = 0; i < 4; ++i)
#pragma unroll
      for (int j = 0; j < 4; ++j) {
        acc[i][j] = __builtin_amdgcn_mfma_f32_16x16x32_f16(ah[i], bh[j], acc[i][j], 0, 0, 0);
        acc[i][j] = __builtin_amdgcn_mfma_f32_16x16x32_f16(ah[i], bl[j], acc[i][j], 0, 0, 0);
        acc[i][j] = __builtin_amdgcn_mfma_f32_16x16x32_f16(al[i], bh[j], acc[i][j], 0, 0, 0);
      }
  }
  // epilogue: C/D frag row = g*4+r, col = ln
#pragma unroll
  for (int i = 0; i < 4; ++i)
#pragma unroll
    for (int j = 0; j < 4; ++j) {
      float* cp = C + (size_t)(mbase + wm + i * 16 + g * 4) * N + nbase + wn + j * 16 + ln;
#pragma unroll
      for (int r = 0; r < 4; ++r) cp[(size_t)r * N] = acc[i][j][r];
    }
}

// ---------------------------------------------------------------------------
// cdelta[h][jr] = sum_d (r_r_bias[h][d] - r_w_bias[h][d]) * rbuf[jr][h*64+d]
// ---------------------------------------------------------------------------
__global__ __launch_bounds__(256) void cdelta_kernel(
    const float* __restrict__ rbuf, const float* __restrict__ rwb,
    const float* __restrict__ rrb, float* __restrict__ cd) {
  int idx = blockIdx.x * 256 + threadIdx.x;  // 32768 total
  int jr = idx >> 4, h = idx & 15;
  const float* rp = rbuf + (size_t)jr * 1024 + h * 64;
  const float* a = rrb + h * 64;
  const float* b = rwb + h * 64;
  float s = 0.f;
#pragma unroll 8
  for (int d = 0; d < 64; ++d) s += (a[d] - b[d]) * rp[d];
  cd[h * 2048 + jr] = s;
}

// ---------------------------------------------------------------------------
// fp16 conversion pre-passes (head-major packed layouts for the MFMA attn)
// ---------------------------------------------------------------------------
__global__ __launch_bounds__(256) void convert_qk(
    const float* __restrict__ qkv, const float* __restrict__ rwb,
    _Float16* __restrict__ qw16, _Float16* __restrict__ k16) {
  const int bid = blockIdx.x;            // b*2048 + trow
  const int b = bid >> 11, trow = bid & 2047;
  const int c = threadIdx.x * 4;         // 0..1023
  const int h = c >> 6, d = c & 63;
  float4 kv = *(const float4*)(qkv + (size_t)bid * 3072 + 1024 + c);
  half4 ko = { (_Float16)kv.x, (_Float16)kv.y, (_Float16)kv.z, (_Float16)kv.w };
  *(half4*)(k16 + (((size_t)(b * 16 + h)) * 2048 + trow) * 64 + d) = ko;
  if (trow >= 1024) {
    int q = trow - 1024;
    float4 qv = *(const float4*)(qkv + (size_t)bid * 3072 + c);
    float4 wv = *(const float4*)(rwb + c);
    half4 qo = { (_Float16)(qv.x + wv.x), (_Float16)(qv.y + wv.y),
                 (_Float16)(qv.z + wv.z), (_Float16)(qv.w + wv.w) };
    *(half4*)(qw16 + (((size_t)(b * 16 + h)) * 1024 + q) * 64 + d) = qo;
  }
}

__global__ __launch_bounds__(256) void convert_r(
    const float* __restrict__ rbuf, _Float16* __restrict__ r16) {
  const int jr = blockIdx.x;             // 0..2047
  const int c = threadIdx.x * 4;
  const int h = c >> 6, d = c & 63;
  float4 rv = *(const float4*)(rbuf + (size_t)jr * 1024 + c);
  half4 ro = { (_Float16)rv.x, (_Float16)rv.y, (_Float16)rv.z, (_Float16)rv.w };
  *(half4*)(r16 + ((size_t)h * 2048 + jr) * 64 + d) = ro;
}

__global__ __launch_bounds__(256) void convert_vt(
    const float* __restrict__ qkv, _Float16* __restrict__ vt16) {
  __shared__ _Float16 T[64][40];
  const int bid = blockIdx.x;            // (b*16+h)*64 + jt
  const int jt = bid & 63, h = (bid >> 6) & 15, b = bid >> 10;
  const int t = threadIdx.x;
  {
    int j = t >> 3, d0 = (t & 7) * 8;
    const float* src = qkv + ((size_t)(b * 2048) + jt * 32 + j) * 3072 + 2048 + h * 64 + d0;
    float4 v0 = *(const float4*)src;
    float4 v1 = *(const float4*)(src + 4);
    T[d0 + 0][j] = (_Float16)v0.x; T[d0 + 1][j] = (_Float16)v0.y;
    T[d0 + 2][j] = (_Float16)v0.z; T[d0 + 3][j] = (_Float16)v0.w;
    T[d0 + 4][j] = (_Float16)v1.x; T[d0 + 5][j] = (_Float16)v1.y;
    T[d0 + 6][j] = (_Float16)v1.z; T[d0 + 7][j] = (_Float16)v1.w;
  }
  __syncthreads();
  {
    int d = t >> 2, j0 = (t & 3) * 8;
    half8 v = *(const half8*)&T[d][j0];
    *(half8*)(vt16 + (((size_t)(b * 16 + h)) * 64 + d) * 2048 + jt * 32 + j0) = v;
  }
}

// ---------------------------------------------------------------------------
// MFMA flash attention (unchanged from R2 — passed at absmax 6.1e-5).
// ---------------------------------------------------------------------------
__global__ __launch_bounds__(256) void attn_mfma(
    const _Float16* __restrict__ qw16, const _Float16* __restrict__ k16,
    const _Float16* __restrict__ vt16, const _Float16* __restrict__ r16,
    const float* __restrict__ cdelta, float* __restrict__ av) {
  __shared__ _Float16 qw_s[64][72];
  __shared__ _Float16 k_s[32][72];
  __shared__ _Float16 r_s[96][72];
  __shared__ _Float16 vt_s[64][40];
  __shared__ _Float16 P_s[64][40];
  __shared__ float cdw_s[96];

  const int qt = blockIdx.x, h = blockIdx.y, b = blockIdx.z;
  const int qbase = qt * 64;
  const int bh = b * 16 + h;
  const int t = threadIdx.x;
  const int lane = t & 63, w = t >> 6;
  const int ln = lane & 15, g = lane >> 4;

#pragma unroll
  for (int i = 0; i < 2; ++i) {
    int idx = t + i * 256;
    int row = idx >> 3, d0 = (idx & 7) * 8;
    *(half8*)&qw_s[row][d0] =
        *(const half8*)(qw16 + ((size_t)bh * 1024 + qbase + row) * 64 + d0);
  }

  f32x4 O[4] = {};
  float mold[4] = {-1e30f, -1e30f, -1e30f, -1e30f};
  float llane[4] = {0.f, 0.f, 0.f, 0.f};
  const int rb = 48 - 16 * w;

  const int ktiles = 2 * qt + 34;
  for (int kt = 0; kt < ktiles; ++kt) {
    const int kbase = kt * 32;
    const int R = kbase - qbase + 960;
    const int climit = qbase + 16 * w + 1039 - kbase;
    __syncthreads();
    {
      int j = t >> 3, d0 = (t & 7) * 8;
      *(half8*)&k_s[j][d0] =
          *(const half8*)(k16 + ((size_t)bh * 2048 + kbase + j) * 64 + d0);
      int dv = t >> 2, jv = (t & 3) * 8;
      *(half8*)&vt_s[dv][jv] =
          *(const half8*)(vt16 + ((size_t)bh * 64 + dv) * 2048 + kbase + jv);
#pragma unroll
      for (int i = 0; i < 3; ++i) {
        int idx = t + i * 256;
        int row = idx >> 3, c8 = (idx & 7) * 8;
        int rr = R + row; rr = rr > 2047 ? 2047 : rr;
        *(half8*)&r_s[row][c8] =
            *(const half8*)(r16 + ((size_t)h * 2048 + rr) * 64 + c8);
      }
      if (t < 96) {
        int rr = R + t; rr = rr > 2047 ? 2047 : rr;
        cdw_s[t] = cdelta[h * 2048 + rr];
      }
    }
    __syncthreads();

    const _Float16* qrow = &qw_s[16 * w + ln][0];
    half8 aq0 = *(const half8*)(qrow + g * 8);
    half8 aq1 = *(const half8*)(qrow + 32 + g * 8);

    f32x4 Sf[2];
#pragma unroll
    for (int jt = 0; jt < 2; ++jt) {
      const _Float16* kr = &k_s[jt * 16 + ln][0];
      half8 b0 = *(const half8*)(kr + g * 8);
      half8 b1 = *(const half8*)(kr + 32 + g * 8);
      f32x4 z = {0.f, 0.f, 0.f, 0.f};
      z = __builtin_amdgcn_mfma_f32_16x16x32_f16(aq0, b0, z, 0, 0, 0);
      z = __builtin_amdgcn_mfma_f32_16x16x32_f16(aq1, b1, z, 0, 0, 0);
      Sf[jt] = z;
    }
    f32x4 Tf[3];
#pragma unroll
    for (int ft = 0; ft < 3; ++ft) {
      const _Float16* rr_ = &r_s[rb + ft * 16 + ln][0];
      half8 b0 = *(const half8*)(rr_ + g * 8);
      half8 b1 = *(const half8*)(rr_ + 32 + g * 8);
      f32x4 z = {0.f, 0.f, 0.f, 0.f};
      z = __builtin_amdgcn_mfma_f32_16x16x32_f16(aq0, b0, z, 0, 0, 0);
      z = __builtin_amdgcn_mfma_f32_16x16x32_f16(aq1, b1, z, 0, 0, 0);
      Tf[ft] = z;
    }

    float sv[2][4];
#pragma unroll
    for (int jt = 0; jt < 2; ++jt) {
#pragma unroll
      for (int r = 0; r < 4; ++r) {
        int cw = jt * 16 + ln + 15 - 4 * g - r;
        int src = (lane & 48) | (cw & 15);
        float t0 = __shfl(Tf[0][r], src, 64);
        float t1 = __shfl(Tf[1][r], src, 64);
        float t2 = __shfl(Tf[2][r], src, 64);
        float tv = (cw < 16) ? t0 : ((cw < 32) ? t1 : t2);
        float s = (Sf[jt][r] + tv + cdw_s[cw + rb]) * 0.125f;
        sv[jt][r] = (cw > climit) ? -1e30f : s;
      }
    }
    float alpha[4];
#pragma unroll
    for (int r = 0; r < 4; ++r) {
      float mx = fmaxf(sv[0][r], sv[1][r]);
      mx = fmaxf(mx, __shfl_xor(mx, 1, 64));
      mx = fmaxf(mx, __shfl_xor(mx, 2, 64));
      mx = fmaxf(mx, __shfl_xor(mx, 4, 64));
      mx = fmaxf(mx, __shfl_xor(mx, 8, 64));
      float mn = fmaxf(mold[r], mx);
      float al = __expf(mold[r] - mn);
      mold[r] = mn;
      float p0 = __expf(sv[0][r] - mn);
      float p1 = __expf(sv[1][r] - mn);
      llane[r] = llane[r] * al + p0 + p1;
      int prow = w * 16 + 4 * g + r;
      P_s[prow][ln] = (_Float16)p0;
      P_s[prow][16 + ln] = (_Float16)p1;
      alpha[r] = al;
    }
#pragma unroll
    for (int dt = 0; dt < 4; ++dt)
#pragma unroll
      for (int r = 0; r < 4; ++r) O[dt][r] *= alpha[r];

    __builtin_amdgcn_s_waitcnt(0);  // drain P_s writes (wave-local)

    half8 pA = *(const half8*)&P_s[w * 16 + ln][g * 8];
#pragma unroll
    for (int dt = 0; dt < 4; ++dt) {
      half8 bv = *(const half8*)&vt_s[dt * 16 + ln][g * 8];
      O[dt] = __builtin_amdgcn_mfma_f32_16x16x32_f16(pA, bv, O[dt], 0, 0, 0);
    }
  }

#pragma unroll
  for (int r = 0; r < 4; ++r) {
    float ls = llane[r];
    ls += __shfl_xor(ls, 1, 64);
    ls += __shfl_xor(ls, 2, 64);
    ls += __shfl_xor(ls, 4, 64);
    ls += __shfl_xor(ls, 8, 64);
    float inv = 1.f / ls;
    int qrow = qbase + 16 * w + 4 * g + r;
    float* op = av + ((size_t)b * 1024 + qrow) * 1024 + h * 64 + ln;
#pragma unroll
    for (int dt = 0; dt < 4; ++dt) op[dt * 16] = O[dt][r] * inv;
  }
}

// ---------------------------------------------------------------------------
extern "C" void kernel_launch(void* const* d_in, const int* in_sizes, int n_in,
                              void* d_out, int out_size, void* d_ws, size_t ws_size,
                              hipStream_t stream) {
  const float* inputs  = (const float*)d_in[0];
  const float* pos_emb = (const float*)d_in[1];
  const float* rwb     = (const float*)d_in[2];
  const float* rrb     = (const float*)d_in[3];
  const float* mems    = (const float*)d_in[4];
  const float* W_w     = (const float*)d_in[5];
  const float* W_r     = (const float*)d_in[6];
  const float* W_o     = (const float*)d_in[7];
  float* out = (float*)d_out;
  float* ws  = (float*)d_ws;

  float* qkv    = ws;                                   // 4*2048*3072 f32
  float* rbuf   = qkv  + (size_t)4 * 2048 * 3072;       // 2048*1024 f32
  float* cdelta = rbuf + (size_t)2048 * 1024;           // 16*2048 f32
  float* av     = cdelta + (size_t)16 * 2048;           // 4*1024*1024 f32
  _Float16* qw16 = (_Float16*)(av + (size_t)4 * 1024 * 1024); // 4*16*1024*64 h
  _Float16* k16  = qw16 + (size_t)4 * 16 * 1024 * 64;         // 4*16*2048*64 h
  _Float16* vt16 = k16  + (size_t)4 * 16 * 2048 * 64;         // 4*16*64*2048 h
  _Float16* r16  = vt16 + (size_t)4 * 16 * 64 * 2048;         // 16*2048*64 h
  _Float16* wwt  = r16  + (size_t)16 * 2048 * 64;             // 3072*2048 h
  _Float16* wrt  = wwt  + (size_t)3072 * 2048;                // 1024*2048 h
  _Float16* wot  = wrt  + (size_t)1024 * 2048;                // 1024*2048 h

  // 0) split+transpose the weight matrices to fp16 hi/lo
  split_w<<<dim3(48, 16), 256, 0, stream>>>(W_w, wwt, 3072);
  split_w<<<dim3(16, 16), 256, 0, stream>>>(W_r, wrt, 1024);
  split_w<<<dim3(16, 16), 256, 0, stream>>>(W_o, wot, 1024);
  // 1) qkv = cat(mems, inputs) @ W_w   (M=8192, N=3072)
  gemm_mfma_split<<<dim3(24, 64), 256, 0, stream>>>(mems, inputs, 1, wwt, qkv, 3072);
  // 2) r = pos_emb @ W_r               (M=2048, N=1024)
  gemm_mfma_split<<<dim3(8, 16), 256, 0, stream>>>(pos_emb, nullptr, 0, wrt, rbuf, 1024);
  // 3) cdelta
  cdelta_kernel<<<128, 256, 0, stream>>>(rbuf, rwb, rrb, cdelta);
  // 4) fp16 packing for attention
  convert_qk<<<8192, 256, 0, stream>>>(qkv, rwb, qw16, k16);
  convert_r<<<2048, 256, 0, stream>>>(rbuf, r16);
  convert_vt<<<4096, 256, 0, stream>>>(qkv, vt16);
  // 5) MFMA flash attention
  attn_mfma<<<dim3(16, 16, 4), 256, 0, stream>>>(qw16, k16, vt16, r16, cdelta, av);
  // 6) out = attn_vec @ W_o            (M=4096, N=1024)
  gemm_mfma_split<<<dim3(8, 32), 256, 0, stream>>>(av, nullptr, 0, wot, out, 1024);
}

// Round 4
// 576.801 us; speedup vs baseline: 5.2992x; 1.1376x over previous
//
#include <hip/hip_runtime.h>
#include <cstdint>
#include <cstddef>

static constexpr int QL = 1024;   // q_len
// k_len = 2048, d_model = 1024, heads = 16, depth = 64

typedef _Float16 half8 __attribute__((ext_vector_type(8)));
typedef _Float16 half4 __attribute__((ext_vector_type(4)));
typedef float f32x4 __attribute__((ext_vector_type(4)));

// ---------------------------------------------------------------------------
// gather: A rows come from cat(mems, inputs) per batch (2048 rows/batch)
// ---------------------------------------------------------------------------
__device__ __forceinline__ const float* gemm_row_ptr(const float* A, const float* A2,
                                                     int r, int gather) {
  if (!gather) return A + (size_t)r * 1024;
  int b = r >> 11, tt = r & 2047;
  if (tt < QL) return A + ((size_t)b * QL + tt) * 1024;    // mems part
  return A2 + ((size_t)b * QL + (tt - QL)) * 1024;         // inputs part
}

// ---------------------------------------------------------------------------
// Pre-pass: W[1024][N] -> Wt[N][2048] fp16, rows = [k-tile 0: hi32|lo32][...]
// ---------------------------------------------------------------------------
__global__ __launch_bounds__(256) void split_w(
    const float* __restrict__ W, _Float16* __restrict__ Wt, int N) {
  __shared__ float T[64][65];
  const int nb = blockIdx.x * 64, kb = blockIdx.y * 64;
  const int t = threadIdx.x;
  {
    int row = t >> 2, c0 = (t & 3) * 16;
    const float* src = W + (size_t)(kb + row) * N + nb + c0;
#pragma unroll
    for (int c = 0; c < 16; c += 4) {
      float4 v = *(const float4*)(src + c);
      T[row][c0 + c + 0] = v.x; T[row][c0 + c + 1] = v.y;
      T[row][c0 + c + 2] = v.z; T[row][c0 + c + 3] = v.w;
    }
  }
  __syncthreads();
  {
    int nrow = t >> 2, ks = (t & 3) * 16;
    half8 hi0, hi1, lo0, lo1;
#pragma unroll
    for (int c = 0; c < 16; ++c) {
      float f = T[ks + c][nrow];
      _Float16 h = (_Float16)f;
      _Float16 l = (_Float16)(f - (float)h);
      if (c < 8) { hi0[c] = h; lo0[c] = l; } else { hi1[c - 8] = h; lo1[c - 8] = l; }
    }
    int kglob = kb + ks;
    int kt = kglob >> 5, pos = kglob & 31;
    _Float16* dst = Wt + (size_t)(nb + nrow) * 2048 + kt * 64 + pos;
    *(half8*)dst = hi0; *(half8*)(dst + 8) = hi1;
    *(half8*)(dst + 32) = lo0; *(half8*)(dst + 40) = lo1;
  }
}

// ---------------------------------------------------------------------------
// Split-fp16 MFMA GEMM (unchanged from R3).
// ---------------------------------------------------------------------------
__global__ __launch_bounds__(256) void gemm_mfma_split(
    const float* __restrict__ A, const float* __restrict__ A2, int gather,
    const _Float16* __restrict__ Bt, float* __restrict__ C, int N) {
  __shared__ _Float16 As[128][72];
  __shared__ _Float16 Bs[128][72];
  const int t = threadIdx.x;
  const int nbase = blockIdx.x * 128, mbase = blockIdx.y * 128;
  const int lane = t & 63, w = t >> 6;
  const int ln = lane & 15, g = lane >> 4;
  const int wm = (w & 1) * 64, wn = (w >> 1) * 64;
  const int ar = t >> 1, asg = (t & 1) * 16;
  const int br = t >> 1, bsg = (t & 1) * 32;
  const float* arow = gemm_row_ptr(A, A2, mbase + ar, gather) + asg;
  const _Float16* brow = Bt + (size_t)(nbase + br) * 2048 + bsg;

  f32x4 acc[4][4] = {};
  for (int kt = 0; kt < 32; ++kt) {
    float4 av0 = *(const float4*)(arow + kt * 32 + 0);
    float4 av1 = *(const float4*)(arow + kt * 32 + 4);
    float4 av2 = *(const float4*)(arow + kt * 32 + 8);
    float4 av3 = *(const float4*)(arow + kt * 32 + 12);
    half8 bv0 = *(const half8*)(brow + kt * 64 + 0);
    half8 bv1 = *(const half8*)(brow + kt * 64 + 8);
    half8 bv2 = *(const half8*)(brow + kt * 64 + 16);
    half8 bv3 = *(const half8*)(brow + kt * 64 + 24);
    half8 ahi0, ahi1, alo0, alo1;
    float fa[16] = {av0.x, av0.y, av0.z, av0.w, av1.x, av1.y, av1.z, av1.w,
                    av2.x, av2.y, av2.z, av2.w, av3.x, av3.y, av3.z, av3.w};
#pragma unroll
    for (int c = 0; c < 16; ++c) {
      _Float16 h = (_Float16)fa[c];
      _Float16 l = (_Float16)(fa[c] - (float)h);
      if (c < 8) { ahi0[c] = h; alo0[c] = l; } else { ahi1[c - 8] = h; alo1[c - 8] = l; }
    }
    __syncthreads();
    *(half8*)&As[ar][asg] = ahi0;      *(half8*)&As[ar][asg + 8] = ahi1;
    *(half8*)&As[ar][32 + asg] = alo0; *(half8*)&As[ar][32 + asg + 8] = alo1;
    *(half8*)&Bs[br][bsg + 0] = bv0;   *(half8*)&Bs[br][bsg + 8] = bv1;
    *(half8*)&Bs[br][bsg + 16] = bv2;  *(half8*)&Bs[br][bsg + 24] = bv3;
    __syncthreads();
    half8 ah[4], al[4], bh[4], bl[4];
#pragma unroll
    for (int i = 0; i < 4; ++i) {
      ah[i] = *(const half8*)&As[wm + i * 16 + ln][g * 8];
      al[i] = *(const half8*)&As[wm + i * 16 + ln][32 + g * 8];
    }
#pragma unroll
    for (int j = 0; j < 4; ++j) {
      bh[j] = *(const half8*)&Bs[wn + j * 16 + ln][g * 8];
      bl[j] = *(const half8*)&Bs[wn + j * 16 + ln][32 + g * 8];
    }
#pragma unroll
    for (int i = 0; i < 4; ++i)
#pragma unroll
      for (int j = 0; j < 4; ++j) {
        acc[i][j] = __builtin_amdgcn_mfma_f32_16x16x32_f16(ah[i], bh[j], acc[i][j], 0, 0, 0);
        acc[i][j] = __builtin_amdgcn_mfma_f32_16x16x32_f16(ah[i], bl[j], acc[i][j], 0, 0, 0);
        acc[i][j] = __builtin_amdgcn_mfma_f32_16x16x32_f16(al[i], bh[j], acc[i][j], 0, 0, 0);
      }
  }
#pragma unroll
  for (int i = 0; i < 4; ++i)
#pragma unroll
    for (int j = 0; j < 4; ++j) {
      float* cp = C + (size_t)(mbase + wm + i * 16 + g * 4) * N + nbase + wn + j * 16 + ln;
#pragma unroll
      for (int r = 0; r < 4; ++r) cp[(size_t)r * N] = acc[i][j][r];
    }
}

// ---------------------------------------------------------------------------
// cdelta[h][jr] = sum_d (r_r_bias[h][d] - r_w_bias[h][d]) * rbuf[jr][h*64+d]
// ---------------------------------------------------------------------------
__global__ __launch_bounds__(256) void cdelta_kernel(
    const float* __restrict__ rbuf, const float* __restrict__ rwb,
    const float* __restrict__ rrb, float* __restrict__ cd) {
  int idx = blockIdx.x * 256 + threadIdx.x;
  int jr = idx >> 4, h = idx & 15;
  const float* rp = rbuf + (size_t)jr * 1024 + h * 64;
  const float* a = rrb + h * 64;
  const float* b = rwb + h * 64;
  float s = 0.f;
#pragma unroll 8
  for (int d = 0; d < 64; ++d) s += (a[d] - b[d]) * rp[d];
  cd[h * 2048 + jr] = s;
}

// ---------------------------------------------------------------------------
// fp16 conversion pre-passes (unchanged)
// ---------------------------------------------------------------------------
__global__ __launch_bounds__(256) void convert_qk(
    const float* __restrict__ qkv, const float* __restrict__ rwb,
    _Float16* __restrict__ qw16, _Float16* __restrict__ k16) {
  const int bid = blockIdx.x;
  const int b = bid >> 11, trow = bid & 2047;
  const int c = threadIdx.x * 4;
  const int h = c >> 6, d = c & 63;
  float4 kv = *(const float4*)(qkv + (size_t)bid * 3072 + 1024 + c);
  half4 ko = { (_Float16)kv.x, (_Float16)kv.y, (_Float16)kv.z, (_Float16)kv.w };
  *(half4*)(k16 + (((size_t)(b * 16 + h)) * 2048 + trow) * 64 + d) = ko;
  if (trow >= 1024) {
    int q = trow - 1024;
    float4 qv = *(const float4*)(qkv + (size_t)bid * 3072 + c);
    float4 wv = *(const float4*)(rwb + c);
    half4 qo = { (_Float16)(qv.x + wv.x), (_Float16)(qv.y + wv.y),
                 (_Float16)(qv.z + wv.z), (_Float16)(qv.w + wv.w) };
    *(half4*)(qw16 + (((size_t)(b * 16 + h)) * 1024 + q) * 64 + d) = qo;
  }
}

__global__ __launch_bounds__(256) void convert_r(
    const float* __restrict__ rbuf, _Float16* __restrict__ r16) {
  const int jr = blockIdx.x;
  const int c = threadIdx.x * 4;
  const int h = c >> 6, d = c & 63;
  float4 rv = *(const float4*)(rbuf + (size_t)jr * 1024 + c);
  half4 ro = { (_Float16)rv.x, (_Float16)rv.y, (_Float16)rv.z, (_Float16)rv.w };
  *(half4*)(r16 + ((size_t)h * 2048 + jr) * 64 + d) = ro;
}

__global__ __launch_bounds__(256) void convert_vt(
    const float* __restrict__ qkv, _Float16* __restrict__ vt16) {
  __shared__ _Float16 T[64][40];
  const int bid = blockIdx.x;
  const int jt = bid & 63, h = (bid >> 6) & 15, b = bid >> 10;
  const int t = threadIdx.x;
  {
    int j = t >> 3, d0 = (t & 7) * 8;
    const float* src = qkv + ((size_t)(b * 2048) + jt * 32 + j) * 3072 + 2048 + h * 64 + d0;
    float4 v0 = *(const float4*)src;
    float4 v1 = *(const float4*)(src + 4);
    T[d0 + 0][j] = (_Float16)v0.x; T[d0 + 1][j] = (_Float16)v0.y;
    T[d0 + 2][j] = (_Float16)v0.z; T[d0 + 3][j] = (_Float16)v0.w;
    T[d0 + 4][j] = (_Float16)v1.x; T[d0 + 5][j] = (_Float16)v1.y;
    T[d0 + 6][j] = (_Float16)v1.z; T[d0 + 7][j] = (_Float16)v1.w;
  }
  __syncthreads();
  {
    int d = t >> 2, j0 = (t & 3) * 8;
    half8 v = *(const half8*)&T[d][j0];
    *(half8*)(vt16 + (((size_t)(b * 16 + h)) * 64 + d) * 2048 + jt * 32 + j0) = v;
  }
}

// ---------------------------------------------------------------------------
// MFMA flash attention v2.
// Block = paired q-tiles (qt, 15-qt) of 64 rows each -> uniform 49 k-tiles.
// K-tile=64, register prefetch, hoisted A-frags, LDS-scratch diag extraction.
// 512 blocks, 4 waves; each wave owns 16 q-rows.
// ---------------------------------------------------------------------------
__global__ __launch_bounds__(256) void attn_mfma2(
    const _Float16* __restrict__ qw16, const _Float16* __restrict__ k16,
    const _Float16* __restrict__ vt16, const _Float16* __restrict__ r16,
    const float* __restrict__ cdelta, float* __restrict__ av) {
  __shared__ __align__(16) float scratch[4][80][24];   // per-wave T window; qw_s overlaid
  __shared__ __align__(16) _Float16 k_s[64][72];
  __shared__ __align__(16) _Float16 vt_s[64][72];
  __shared__ __align__(16) _Float16 r_s[128][72];
  __shared__ __align__(16) _Float16 P_s[4][16][72];
  __shared__ float cdw_s[128];
  _Float16 (*qw_s)[72] = (_Float16 (*)[72])&scratch[0][0][0];

  const int pr = blockIdx.x, h = blockIdx.y, b = blockIdx.z;
  const int bh = b * 16 + h;
  const int t = threadIdx.x;
  const int lane = t & 63, w = t >> 6;
  const int ln = lane & 15, g = lane >> 4;
  const int rb = 48 - 16 * w;          // wave window base inside 128-row block window

  const int s_row4 = t >> 2, s_c16 = (t & 3) * 16;   // qw/k/vt staging split
  const int s_row2 = t >> 1, s_c32 = (t & 1) * 32;   // r staging split

  const float* cdh = cdelta + h * 2048;
  const _Float16* kb_p = k16 + (size_t)bh * 2048 * 64;
  const _Float16* vb_p = vt16 + (size_t)bh * 64 * 2048;
  const _Float16* rb_p = r16 + (size_t)h * 2048 * 64;
  const _Float16* qb_p = qw16 + (size_t)bh * 1024 * 64;

#pragma unroll 1
  for (int phase = 0; phase < 2; ++phase) {
    const int qt = phase ? (15 - pr) : pr;
    const int qbase = qt * 64;
    const int ktiles = qt + 17;

    __syncthreads();   // prev phase done with scratch region
    {
      const _Float16* src = qb_p + (size_t)(qbase + s_row4) * 64 + s_c16;
      half8 a0 = *(const half8*)src;
      half8 a1 = *(const half8*)(src + 8);
      *(half8*)&qw_s[s_row4][s_c16] = a0;
      *(half8*)&qw_s[s_row4][s_c16 + 8] = a1;
    }
    __syncthreads();
    half8 aq0 = *(const half8*)&qw_s[16 * w + ln][g * 8];
    half8 aq1 = *(const half8*)&qw_s[16 * w + ln][32 + g * 8];
    __syncthreads();   // aq reads drained before scratch reuse

    f32x4 O[4] = {};
    float mold[4] = {-1e30f, -1e30f, -1e30f, -1e30f};
    float llane[4] = {0.f, 0.f, 0.f, 0.f};

    // prefetch tile 0
    half8 kp0, kp1, vp0, vp1, rp0, rp1, rp2, rp3;
    float cdp = 0.f;
    {
      const int R0 = 0 - qbase + 960;
      const _Float16* kp = kb_p + (size_t)s_row4 * 64 + s_c16;
      kp0 = *(const half8*)kp; kp1 = *(const half8*)(kp + 8);
      const _Float16* vp = vb_p + (size_t)s_row4 * 2048 + s_c16;
      vp0 = *(const half8*)vp; vp1 = *(const half8*)(vp + 8);
      int rr = R0 + s_row2; rr = rr > 2047 ? 2047 : rr;
      const _Float16* rp = rb_p + (size_t)rr * 64 + s_c32;
      rp0 = *(const half8*)rp;        rp1 = *(const half8*)(rp + 8);
      rp2 = *(const half8*)(rp + 16); rp3 = *(const half8*)(rp + 24);
      if (t < 128) { int cr = R0 + t; cr = cr > 2047 ? 2047 : cr; cdp = cdh[cr]; }
    }

    for (int kt = 0; kt < ktiles; ++kt) {
      const int kbase = kt * 64;
      __syncthreads();
      *(half8*)&k_s[s_row4][s_c16] = kp0;      *(half8*)&k_s[s_row4][s_c16 + 8] = kp1;
      *(half8*)&vt_s[s_row4][s_c16] = vp0;     *(half8*)&vt_s[s_row4][s_c16 + 8] = vp1;
      *(half8*)&r_s[s_row2][s_c32] = rp0;      *(half8*)&r_s[s_row2][s_c32 + 8] = rp1;
      *(half8*)&r_s[s_row2][s_c32 + 16] = rp2; *(half8*)&r_s[s_row2][s_c32 + 24] = rp3;
      if (t < 128) cdw_s[t] = cdp;
      __syncthreads();
      if (kt + 1 < ktiles) {  // prefetch next tile during compute
        const int kb2 = kbase + 64, R2 = kb2 - qbase + 960;
        const _Float16* kp = kb_p + (size_t)(kb2 + s_row4) * 64 + s_c16;
        kp0 = *(const half8*)kp; kp1 = *(const half8*)(kp + 8);
        const _Float16* vp = vb_p + (size_t)s_row4 * 2048 + kb2 + s_c16;
        vp0 = *(const half8*)vp; vp1 = *(const half8*)(vp + 8);
        int rr = R2 + s_row2; rr = rr > 2047 ? 2047 : rr;
        const _Float16* rp = rb_p + (size_t)rr * 64 + s_c32;
        rp0 = *(const half8*)rp;        rp1 = *(const half8*)(rp + 8);
        rp2 = *(const half8*)(rp + 16); rp3 = *(const half8*)(rp + 24);
        if (t < 128) { int cr = R2 + t; cr = cr > 2047 ? 2047 : cr; cdp = cdh[cr]; }
      }

      // ---- QK^T: 4 j-tiles ----
      f32x4 Sf[4];
#pragma unroll
      for (int jt = 0; jt < 4; ++jt) {
        half8 b0 = *(const half8*)&k_s[jt * 16 + ln][g * 8];
        half8 b1 = *(const half8*)&k_s[jt * 16 + ln][32 + g * 8];
        f32x4 z = {0.f, 0.f, 0.f, 0.f};
        z = __builtin_amdgcn_mfma_f32_16x16x32_f16(aq0, b0, z, 0, 0, 0);
        z = __builtin_amdgcn_mfma_f32_16x16x32_f16(aq1, b1, z, 0, 0, 0);
        Sf[jt] = z;
      }
      // ---- T window (5 col-tiles) + cdelta, into per-wave scratch ----
#pragma unroll
      for (int ft = 0; ft < 5; ++ft) {
        half8 b0 = *(const half8*)&r_s[rb + ft * 16 + ln][g * 8];
        half8 b1 = *(const half8*)&r_s[rb + ft * 16 + ln][32 + g * 8];
        f32x4 z = {0.f, 0.f, 0.f, 0.f};
        z = __builtin_amdgcn_mfma_f32_16x16x32_f16(aq0, b0, z, 0, 0, 0);
        z = __builtin_amdgcn_mfma_f32_16x16x32_f16(aq1, b1, z, 0, 0, 0);
        float cdv = cdw_s[rb + ft * 16 + ln];
        z[0] += cdv; z[1] += cdv; z[2] += cdv; z[3] += cdv;
        *(f32x4*)&scratch[w][ft * 16 + ln][4 * g] = z;
      }
      // ---- scores: read shifted diagonal, scale, mask ----
      const int climit = qbase + 16 * w + 1039 - kbase;
      float sv[4][4];
#pragma unroll
      for (int jt = 0; jt < 4; ++jt)
#pragma unroll
        for (int r = 0; r < 4; ++r) {
          int cw = jt * 16 + ln + 15 - 4 * g - r;
          float tv = scratch[w][cw][4 * g + r];
          float s = (Sf[jt][r] + tv) * 0.125f;
          sv[jt][r] = (cw > climit) ? -1e30f : s;
        }
      // ---- online softmax (rows inside 16-lane groups) ----
      float alpha[4];
#pragma unroll
      for (int r = 0; r < 4; ++r) {
        float mx = fmaxf(fmaxf(sv[0][r], sv[1][r]), fmaxf(sv[2][r], sv[3][r]));
        mx = fmaxf(mx, __shfl_xor(mx, 1, 64));
        mx = fmaxf(mx, __shfl_xor(mx, 2, 64));
        mx = fmaxf(mx, __shfl_xor(mx, 4, 64));
        mx = fmaxf(mx, __shfl_xor(mx, 8, 64));
        float mn = fmaxf(mold[r], mx);
        float al = __expf(mold[r] - mn);
        mold[r] = mn;
        float psum = 0.f;
#pragma unroll
        for (int jt = 0; jt < 4; ++jt) {
          float p = __expf(sv[jt][r] - mn);
          psum += p;
          P_s[w][4 * g + r][jt * 16 + ln] = (_Float16)p;
        }
        llane[r] = llane[r] * al + psum;
        alpha[r] = al;
      }
#pragma unroll
      for (int dt = 0; dt < 4; ++dt)
#pragma unroll
        for (int r = 0; r < 4; ++r) O[dt][r] *= alpha[r];
      // ---- PV ----
      half8 pA0 = *(const half8*)&P_s[w][ln][g * 8];
      half8 pA1 = *(const half8*)&P_s[w][ln][32 + g * 8];
#pragma unroll
      for (int dt = 0; dt < 4; ++dt) {
        half8 b0 = *(const half8*)&vt_s[dt * 16 + ln][g * 8];
        half8 b1 = *(const half8*)&vt_s[dt * 16 + ln][32 + g * 8];
        O[dt] = __builtin_amdgcn_mfma_f32_16x16x32_f16(pA0, b0, O[dt], 0, 0, 0);
        O[dt] = __builtin_amdgcn_mfma_f32_16x16x32_f16(pA1, b1, O[dt], 0, 0, 0);
      }
    }

    // ---- epilogue ----
#pragma unroll
    for (int r = 0; r < 4; ++r) {
      float ls = llane[r];
      ls += __shfl_xor(ls, 1, 64);
      ls += __shfl_xor(ls, 2, 64);
      ls += __shfl_xor(ls, 4, 64);
      ls += __shfl_xor(ls, 8, 64);
      float inv = 1.f / ls;
      int qrow = qbase + 16 * w + 4 * g + r;
      float* op = av + ((size_t)b * 1024 + qrow) * 1024 + h * 64 + ln;
#pragma unroll
      for (int dt = 0; dt < 4; ++dt) op[dt * 16] = O[dt][r] * inv;
    }
  }
}

// ---------------------------------------------------------------------------
extern "C" void kernel_launch(void* const* d_in, const int* in_sizes, int n_in,
                              void* d_out, int out_size, void* d_ws, size_t ws_size,
                              hipStream_t stream) {
  const float* inputs  = (const float*)d_in[0];
  const float* pos_emb = (const float*)d_in[1];
  const float* rwb     = (const float*)d_in[2];
  const float* rrb     = (const float*)d_in[3];
  const float* mems    = (const float*)d_in[4];
  const float* W_w     = (const float*)d_in[5];
  const float* W_r     = (const float*)d_in[6];
  const float* W_o     = (const float*)d_in[7];
  float* out = (float*)d_out;
  float* ws  = (float*)d_ws;

  float* qkv    = ws;                                   // 4*2048*3072 f32
  float* rbuf   = qkv  + (size_t)4 * 2048 * 3072;       // 2048*1024 f32
  float* cdelta = rbuf + (size_t)2048 * 1024;           // 16*2048 f32
  float* av     = cdelta + (size_t)16 * 2048;           // 4*1024*1024 f32
  _Float16* qw16 = (_Float16*)(av + (size_t)4 * 1024 * 1024); // 4*16*1024*64 h
  _Float16* k16  = qw16 + (size_t)4 * 16 * 1024 * 64;         // 4*16*2048*64 h
  _Float16* vt16 = k16  + (size_t)4 * 16 * 2048 * 64;         // 4*16*64*2048 h
  _Float16* r16  = vt16 + (size_t)4 * 16 * 64 * 2048;         // 16*2048*64 h
  _Float16* wwt  = r16  + (size_t)16 * 2048 * 64;             // 3072*2048 h
  _Float16* wrt  = wwt  + (size_t)3072 * 2048;                // 1024*2048 h
  _Float16* wot  = wrt  + (size_t)1024 * 2048;                // 1024*2048 h

  // 0) split+transpose weights to fp16 hi/lo
  split_w<<<dim3(48, 16), 256, 0, stream>>>(W_w, wwt, 3072);
  split_w<<<dim3(16, 16), 256, 0, stream>>>(W_r, wrt, 1024);
  split_w<<<dim3(16, 16), 256, 0, stream>>>(W_o, wot, 1024);
  // 1) qkv = cat(mems, inputs) @ W_w   (M=8192, N=3072)
  gemm_mfma_split<<<dim3(24, 64), 256, 0, stream>>>(mems, inputs, 1, wwt, qkv, 3072);
  // 2) r = pos_emb @ W_r               (M=2048, N=1024)
  gemm_mfma_split<<<dim3(8, 16), 256, 0, stream>>>(pos_emb, nullptr, 0, wrt, rbuf, 1024);
  // 3) cdelta
  cdelta_kernel<<<128, 256, 0, stream>>>(rbuf, rwb, rrb, cdelta);
  // 4) fp16 packing for attention
  convert_qk<<<8192, 256, 0, stream>>>(qkv, rwb, qw16, k16);
  convert_r<<<2048, 256, 0, stream>>>(rbuf, r16);
  convert_vt<<<4096, 256, 0, stream>>>(qkv, vt16);
  // 5) MFMA flash attention v2 (paired q-tiles, uniform work)
  attn_mfma2<<<dim3(8, 16, 4), 256, 0, stream>>>(qw16, k16, vt16, r16, cdelta, av);
  // 6) out = attn_vec @ W_o            (M=4096, N=1024)
  gemm_mfma_split<<<dim3(8, 32), 256, 0, stream>>>(av, nullptr, 0, wot, out, 1024);
}

// Round 5
// 462.855 us; speedup vs baseline: 6.6038x; 1.2462x over previous
//
#include <hip/hip_runtime.h>
#include <cstdint>
#include <cstddef>

static constexpr int QL = 1024;   // q_len
// k_len = 2048, d_model = 1024, heads = 16, depth = 64

typedef _Float16 half8 __attribute__((ext_vector_type(8)));
typedef _Float16 half4 __attribute__((ext_vector_type(4)));
typedef float f32x4 __attribute__((ext_vector_type(4)));

// ---------------------------------------------------------------------------
// gather: A rows come from cat(mems, inputs) per batch (2048 rows/batch)
// ---------------------------------------------------------------------------
__device__ __forceinline__ const float* gemm_row_ptr(const float* A, const float* A2,
                                                     int r, int gather) {
  if (!gather) return A + (size_t)r * 1024;
  int b = r >> 11, tt = r & 2047;
  if (tt < QL) return A + ((size_t)b * QL + tt) * 1024;    // mems part
  return A2 + ((size_t)b * QL + (tt - QL)) * 1024;         // inputs part
}

// ---------------------------------------------------------------------------
// fp32 -> fp16 row conversion (optionally gathered from cat(mems,inputs))
// ---------------------------------------------------------------------------
__global__ __launch_bounds__(256) void convert_a16(
    const float* __restrict__ A, const float* __restrict__ A2, int gather,
    _Float16* __restrict__ dst) {
  const int row = blockIdx.x;
  const int c = threadIdx.x * 4;
  const float* src = gemm_row_ptr(A, A2, row, gather);
  float4 v = *(const float4*)(src + c);
  half4 o = { (_Float16)v.x, (_Float16)v.y, (_Float16)v.z, (_Float16)v.w };
  *(half4*)(dst + (size_t)row * 1024 + c) = o;
}

// ---------------------------------------------------------------------------
// Pre-pass: W[1024][N] -> Wt[N][2048] fp16, rows = [k-tile: hi32|lo32][...]
// ---------------------------------------------------------------------------
__global__ __launch_bounds__(256) void split_w(
    const float* __restrict__ W, _Float16* __restrict__ Wt, int N) {
  __shared__ float T[64][65];
  const int nb = blockIdx.x * 64, kb = blockIdx.y * 64;
  const int t = threadIdx.x;
  {
    int row = t >> 2, c0 = (t & 3) * 16;
    const float* src = W + (size_t)(kb + row) * N + nb + c0;
#pragma unroll
    for (int c = 0; c < 16; c += 4) {
      float4 v = *(const float4*)(src + c);
      T[row][c0 + c + 0] = v.x; T[row][c0 + c + 1] = v.y;
      T[row][c0 + c + 2] = v.z; T[row][c0 + c + 3] = v.w;
    }
  }
  __syncthreads();
  {
    int nrow = t >> 2, ks = (t & 3) * 16;
    half8 hi0, hi1, lo0, lo1;
#pragma unroll
    for (int c = 0; c < 16; ++c) {
      float f = T[ks + c][nrow];
      _Float16 h = (_Float16)f;
      _Float16 l = (_Float16)(f - (float)h);
      if (c < 8) { hi0[c] = h; lo0[c] = l; } else { hi1[c - 8] = h; lo1[c - 8] = l; }
    }
    int kglob = kb + ks;
    int kt = kglob >> 5, pos = kglob & 31;
    _Float16* dst = Wt + (size_t)(nb + nrow) * 2048 + kt * 64 + pos;
    *(half8*)dst = hi0; *(half8*)(dst + 8) = hi1;
    *(half8*)(dst + 32) = lo0; *(half8*)(dst + 40) = lo1;
  }
}

// ---------------------------------------------------------------------------
// 2-term split GEMM: C = A16 @ W  ~=  A@Whi + A@Wlo   (A already fp16)
// 128x128 tile, BK=32, 4 waves x (64x64). Fused mode-specific epilogues:
//   mode 0: qkv -> qw16 (+r_w_bias) / k16 / vt16 (transposed), N=3072
//   mode 1: r   -> r16 [h][jr][d], N=1024
//   mode 2: out -> fp32 C, N=1024
// ---------------------------------------------------------------------------
__global__ __launch_bounds__(256) void gemm2(
    const _Float16* __restrict__ A16, const _Float16* __restrict__ Bt,
    int mode, const float* __restrict__ rwb,
    _Float16* __restrict__ d_q, _Float16* __restrict__ d_k,
    _Float16* __restrict__ d_v, float* __restrict__ d_f) {
  const int N = (mode == 0) ? 3072 : 1024;
  const int nbase = blockIdx.x * 128, mbase = blockIdx.y * 128;
  // qkv: skip blocks whose q-columns are entirely unused (rows tt<1024)
  if (mode == 0 && nbase < 1024 && (mbase & 1024) == 0) return;

  __shared__ __align__(16) _Float16 As[128][40];
  __shared__ __align__(16) _Float16 Bs[128][72];
  const int t = threadIdx.x;
  const int lane = t & 63, w = t >> 6;
  const int ln = lane & 15, g = lane >> 4;
  const int wm = (w & 1) * 64, wn = (w >> 1) * 64;
  const int ar = t >> 1, aseg = (t & 1) * 16;
  const int br = t >> 1, bseg = (t & 1) * 32;
  const _Float16* arow = A16 + (size_t)(mbase + ar) * 1024 + aseg;
  const _Float16* brow = Bt + (size_t)(nbase + br) * 2048 + bseg;

  f32x4 acc[4][4] = {};
  for (int kt = 0; kt < 32; ++kt) {
    half8 a0 = *(const half8*)(arow + kt * 32);
    half8 a1 = *(const half8*)(arow + kt * 32 + 8);
    half8 b0 = *(const half8*)(brow + kt * 64 + 0);
    half8 b1 = *(const half8*)(brow + kt * 64 + 8);
    half8 b2 = *(const half8*)(brow + kt * 64 + 16);
    half8 b3 = *(const half8*)(brow + kt * 64 + 24);
    __syncthreads();
    *(half8*)&As[ar][aseg] = a0;      *(half8*)&As[ar][aseg + 8] = a1;
    *(half8*)&Bs[br][bseg + 0] = b0;  *(half8*)&Bs[br][bseg + 8] = b1;
    *(half8*)&Bs[br][bseg + 16] = b2; *(half8*)&Bs[br][bseg + 24] = b3;
    __syncthreads();
    half8 ah[4], bh[4], bl[4];
#pragma unroll
    for (int i = 0; i < 4; ++i)
      ah[i] = *(const half8*)&As[wm + i * 16 + ln][g * 8];
#pragma unroll
    for (int j = 0; j < 4; ++j) {
      bh[j] = *(const half8*)&Bs[wn + j * 16 + ln][g * 8];
      bl[j] = *(const half8*)&Bs[wn + j * 16 + ln][32 + g * 8];
    }
#pragma unroll
    for (int i = 0; i < 4; ++i)
#pragma unroll
      for (int j = 0; j < 4; ++j) {
        acc[i][j] = __builtin_amdgcn_mfma_f32_16x16x32_f16(ah[i], bh[j], acc[i][j], 0, 0, 0);
        acc[i][j] = __builtin_amdgcn_mfma_f32_16x16x32_f16(ah[i], bl[j], acc[i][j], 0, 0, 0);
      }
  }

  // ---------------- epilogues ----------------
  if (mode == 2) {
#pragma unroll
    for (int i = 0; i < 4; ++i)
#pragma unroll
      for (int j = 0; j < 4; ++j) {
        float* cp = d_f + (size_t)(mbase + wm + i * 16 + g * 4) * 1024 + nbase + wn + j * 16 + ln;
#pragma unroll
        for (int r = 0; r < 4; ++r) cp[(size_t)r * 1024] = acc[i][j][r];
      }
    return;
  }
  if (mode == 1) {
#pragma unroll
    for (int j = 0; j < 4; ++j) {
      int n = nbase + wn + j * 16 + ln;
      int h = n >> 6, d = n & 63;
#pragma unroll
      for (int i = 0; i < 4; ++i) {
        int m0 = mbase + wm + i * 16 + g * 4;
        _Float16* rp = d_q + ((size_t)h * 2048 + m0) * 64 + d;   // d_q = r16
#pragma unroll
        for (int r = 0; r < 4; ++r) rp[(size_t)r * 64] = (_Float16)acc[i][j][r];
      }
    }
    return;
  }
  // mode 0: qkv fused scatter
#pragma unroll
  for (int j = 0; j < 4; ++j) {
    int n = nbase + wn + j * 16 + ln;
    int sec = n >> 10;              // 0=q 1=k 2=v
    int c2 = n & 1023, h = c2 >> 6, d = c2 & 63;
    float bias = (sec == 0) ? rwb[c2] : 0.f;
#pragma unroll
    for (int i = 0; i < 4; ++i) {
      int m0 = mbase + wm + i * 16 + g * 4;
      int b = m0 >> 11, tt0 = m0 & 2047;
      size_t bh = (size_t)(b * 16 + h);
#pragma unroll
      for (int r = 0; r < 4; ++r) {
        int tt = tt0 + r;
        float v = acc[i][j][r];
        if (sec == 0) {
          if (tt >= 1024)
            d_q[(bh * 1024 + (tt - 1024)) * 64 + d] = (_Float16)(v + bias);
        } else if (sec == 1) {
          d_k[(bh * 2048 + tt) * 64 + d] = (_Float16)v;
        } else {
          d_v[(bh * 64 + d) * 2048 + tt] = (_Float16)v;
        }
      }
    }
  }
}

// ---------------------------------------------------------------------------
// cdelta[h][jr] = sum_d (r_r_bias - r_w_bias)[h][d] * r16[h][jr][d]
// ---------------------------------------------------------------------------
__global__ __launch_bounds__(256) void cdelta_kernel(
    const _Float16* __restrict__ r16, const float* __restrict__ rwb,
    const float* __restrict__ rrb, float* __restrict__ cd) {
  int idx = blockIdx.x * 256 + threadIdx.x;
  int jr = idx >> 4, h = idx & 15;
  const _Float16* rp = r16 + ((size_t)h * 2048 + jr) * 64;
  const float* a = rrb + h * 64;
  const float* b = rwb + h * 64;
  float s = 0.f;
#pragma unroll 8
  for (int d = 0; d < 64; ++d) s += (a[d] - b[d]) * (float)rp[d];
  cd[h * 2048 + jr] = s;
}

// ---------------------------------------------------------------------------
// MFMA flash attention v2 (R4 structure; epilogue now writes fp16 av16).
// ---------------------------------------------------------------------------
__global__ __launch_bounds__(256) void attn_mfma2(
    const _Float16* __restrict__ qw16, const _Float16* __restrict__ k16,
    const _Float16* __restrict__ vt16, const _Float16* __restrict__ r16,
    const float* __restrict__ cdelta, _Float16* __restrict__ av16) {
  __shared__ __align__(16) float scratch[4][80][24];   // per-wave T window; qw_s overlaid
  __shared__ __align__(16) _Float16 k_s[64][72];
  __shared__ __align__(16) _Float16 vt_s[64][72];
  __shared__ __align__(16) _Float16 r_s[128][72];
  __shared__ __align__(16) _Float16 P_s[4][16][72];
  __shared__ float cdw_s[128];
  _Float16 (*qw_s)[72] = (_Float16 (*)[72])&scratch[0][0][0];

  const int pr = blockIdx.x, h = blockIdx.y, b = blockIdx.z;
  const int bh = b * 16 + h;
  const int t = threadIdx.x;
  const int lane = t & 63, w = t >> 6;
  const int ln = lane & 15, g = lane >> 4;
  const int rb = 48 - 16 * w;

  const int s_row4 = t >> 2, s_c16 = (t & 3) * 16;
  const int s_row2 = t >> 1, s_c32 = (t & 1) * 32;

  const float* cdh = cdelta + h * 2048;
  const _Float16* kb_p = k16 + (size_t)bh * 2048 * 64;
  const _Float16* vb_p = vt16 + (size_t)bh * 64 * 2048;
  const _Float16* rb_p = r16 + (size_t)h * 2048 * 64;
  const _Float16* qb_p = qw16 + (size_t)bh * 1024 * 64;

#pragma unroll 1
  for (int phase = 0; phase < 2; ++phase) {
    const int qt = phase ? (15 - pr) : pr;
    const int qbase = qt * 64;
    const int ktiles = qt + 17;

    __syncthreads();
    {
      const _Float16* src = qb_p + (size_t)(qbase + s_row4) * 64 + s_c16;
      half8 a0 = *(const half8*)src;
      half8 a1 = *(const half8*)(src + 8);
      *(half8*)&qw_s[s_row4][s_c16] = a0;
      *(half8*)&qw_s[s_row4][s_c16 + 8] = a1;
    }
    __syncthreads();
    half8 aq0 = *(const half8*)&qw_s[16 * w + ln][g * 8];
    half8 aq1 = *(const half8*)&qw_s[16 * w + ln][32 + g * 8];
    __syncthreads();

    f32x4 O[4] = {};
    float mold[4] = {-1e30f, -1e30f, -1e30f, -1e30f};
    float llane[4] = {0.f, 0.f, 0.f, 0.f};

    half8 kp0, kp1, vp0, vp1, rp0, rp1, rp2, rp3;
    float cdp = 0.f;
    {
      const int R0 = 0 - qbase + 960;
      const _Float16* kp = kb_p + (size_t)s_row4 * 64 + s_c16;
      kp0 = *(const half8*)kp; kp1 = *(const half8*)(kp + 8);
      const _Float16* vp = vb_p + (size_t)s_row4 * 2048 + s_c16;
      vp0 = *(const half8*)vp; vp1 = *(const half8*)(vp + 8);
      int rr = R0 + s_row2; rr = rr > 2047 ? 2047 : rr;
      const _Float16* rp = rb_p + (size_t)rr * 64 + s_c32;
      rp0 = *(const half8*)rp;        rp1 = *(const half8*)(rp + 8);
      rp2 = *(const half8*)(rp + 16); rp3 = *(const half8*)(rp + 24);
      if (t < 128) { int cr = R0 + t; cr = cr > 2047 ? 2047 : cr; cdp = cdh[cr]; }
    }

    for (int kt = 0; kt < ktiles; ++kt) {
      const int kbase = kt * 64;
      __syncthreads();
      *(half8*)&k_s[s_row4][s_c16] = kp0;      *(half8*)&k_s[s_row4][s_c16 + 8] = kp1;
      *(half8*)&vt_s[s_row4][s_c16] = vp0;     *(half8*)&vt_s[s_row4][s_c16 + 8] = vp1;
      *(half8*)&r_s[s_row2][s_c32] = rp0;      *(half8*)&r_s[s_row2][s_c32 + 8] = rp1;
      *(half8*)&r_s[s_row2][s_c32 + 16] = rp2; *(half8*)&r_s[s_row2][s_c32 + 24] = rp3;
      if (t < 128) cdw_s[t] = cdp;
      __syncthreads();
      if (kt + 1 < ktiles) {
        const int kb2 = kbase + 64, R2 = kb2 - qbase + 960;
        const _Float16* kp = kb_p + (size_t)(kb2 + s_row4) * 64 + s_c16;
        kp0 = *(const half8*)kp; kp1 = *(const half8*)(kp + 8);
        const _Float16* vp = vb_p + (size_t)s_row4 * 2048 + kb2 + s_c16;
        vp0 = *(const half8*)vp; vp1 = *(const half8*)(vp + 8);
        int rr = R2 + s_row2; rr = rr > 2047 ? 2047 : rr;
        const _Float16* rp = rb_p + (size_t)rr * 64 + s_c32;
        rp0 = *(const half8*)rp;        rp1 = *(const half8*)(rp + 8);
        rp2 = *(const half8*)(rp + 16); rp3 = *(const half8*)(rp + 24);
        if (t < 128) { int cr = R2 + t; cr = cr > 2047 ? 2047 : cr; cdp = cdh[cr]; }
      }

      f32x4 Sf[4];
#pragma unroll
      for (int jt = 0; jt < 4; ++jt) {
        half8 b0 = *(const half8*)&k_s[jt * 16 + ln][g * 8];
        half8 b1 = *(const half8*)&k_s[jt * 16 + ln][32 + g * 8];
        f32x4 z = {0.f, 0.f, 0.f, 0.f};
        z = __builtin_amdgcn_mfma_f32_16x16x32_f16(aq0, b0, z, 0, 0, 0);
        z = __builtin_amdgcn_mfma_f32_16x16x32_f16(aq1, b1, z, 0, 0, 0);
        Sf[jt] = z;
      }
#pragma unroll
      for (int ft = 0; ft < 5; ++ft) {
        half8 b0 = *(const half8*)&r_s[rb + ft * 16 + ln][g * 8];
        half8 b1 = *(const half8*)&r_s[rb + ft * 16 + ln][32 + g * 8];
        f32x4 z = {0.f, 0.f, 0.f, 0.f};
        z = __builtin_amdgcn_mfma_f32_16x16x32_f16(aq0, b0, z, 0, 0, 0);
        z = __builtin_amdgcn_mfma_f32_16x16x32_f16(aq1, b1, z, 0, 0, 0);
        float cdv = cdw_s[rb + ft * 16 + ln];
        z[0] += cdv; z[1] += cdv; z[2] += cdv; z[3] += cdv;
        *(f32x4*)&scratch[w][ft * 16 + ln][4 * g] = z;
      }
      const int climit = qbase + 16 * w + 1039 - kbase;
      float sv[4][4];
#pragma unroll
      for (int jt = 0; jt < 4; ++jt)
#pragma unroll
        for (int r = 0; r < 4; ++r) {
          int cw = jt * 16 + ln + 15 - 4 * g - r;
          float tv = scratch[w][cw][4 * g + r];
          float s = (Sf[jt][r] + tv) * 0.125f;
          sv[jt][r] = (cw > climit) ? -1e30f : s;
        }
      float alpha[4];
#pragma unroll
      for (int r = 0; r < 4; ++r) {
        float mx = fmaxf(fmaxf(sv[0][r], sv[1][r]), fmaxf(sv[2][r], sv[3][r]));
        mx = fmaxf(mx, __shfl_xor(mx, 1, 64));
        mx = fmaxf(mx, __shfl_xor(mx, 2, 64));
        mx = fmaxf(mx, __shfl_xor(mx, 4, 64));
        mx = fmaxf(mx, __shfl_xor(mx, 8, 64));
        float mn = fmaxf(mold[r], mx);
        float al = __expf(mold[r] - mn);
        mold[r] = mn;
        float psum = 0.f;
#pragma unroll
        for (int jt = 0; jt < 4; ++jt) {
          float p = __expf(sv[jt][r] - mn);
          psum += p;
          P_s[w][4 * g + r][jt * 16 + ln] = (_Float16)p;
        }
        llane[r] = llane[r] * al + psum;
        alpha[r] = al;
      }
#pragma unroll
      for (int dt = 0; dt < 4; ++dt)
#pragma unroll
        for (int r = 0; r < 4; ++r) O[dt][r] *= alpha[r];
      half8 pA0 = *(const half8*)&P_s[w][ln][g * 8];
      half8 pA1 = *(const half8*)&P_s[w][ln][32 + g * 8];
#pragma unroll
      for (int dt = 0; dt < 4; ++dt) {
        half8 b0 = *(const half8*)&vt_s[dt * 16 + ln][g * 8];
        half8 b1 = *(const half8*)&vt_s[dt * 16 + ln][32 + g * 8];
        O[dt] = __builtin_amdgcn_mfma_f32_16x16x32_f16(pA0, b0, O[dt], 0, 0, 0);
        O[dt] = __builtin_amdgcn_mfma_f32_16x16x32_f16(pA1, b1, O[dt], 0, 0, 0);
      }
    }

#pragma unroll
    for (int r = 0; r < 4; ++r) {
      float ls = llane[r];
      ls += __shfl_xor(ls, 1, 64);
      ls += __shfl_xor(ls, 2, 64);
      ls += __shfl_xor(ls, 4, 64);
      ls += __shfl_xor(ls, 8, 64);
      float inv = 1.f / ls;
      int qrow = qbase + 16 * w + 4 * g + r;
      _Float16* op = av16 + ((size_t)b * 1024 + qrow) * 1024 + h * 64 + ln;
#pragma unroll
      for (int dt = 0; dt < 4; ++dt) op[dt * 16] = (_Float16)(O[dt][r] * inv);
    }
  }
}

// ---------------------------------------------------------------------------
extern "C" void kernel_launch(void* const* d_in, const int* in_sizes, int n_in,
                              void* d_out, int out_size, void* d_ws, size_t ws_size,
                              hipStream_t stream) {
  const float* inputs  = (const float*)d_in[0];
  const float* pos_emb = (const float*)d_in[1];
  const float* rwb     = (const float*)d_in[2];
  const float* rrb     = (const float*)d_in[3];
  const float* mems    = (const float*)d_in[4];
  const float* W_w     = (const float*)d_in[5];
  const float* W_r     = (const float*)d_in[6];
  const float* W_o     = (const float*)d_in[7];
  float* out = (float*)d_out;

  _Float16* hws = (_Float16*)d_ws;
  _Float16* a16   = hws;                                    // 8192*1024
  _Float16* pe16  = a16  + (size_t)8192 * 1024;             // 2048*1024
  _Float16* qw16  = pe16 + (size_t)2048 * 1024;             // 64*1024*64
  _Float16* k16   = qw16 + (size_t)64 * 1024 * 64;          // 64*2048*64
  _Float16* vt16  = k16  + (size_t)64 * 2048 * 64;          // 64*64*2048
  _Float16* r16   = vt16 + (size_t)64 * 64 * 2048;          // 16*2048*64
  _Float16* av16  = r16  + (size_t)16 * 2048 * 64;          // 4096*1024
  _Float16* wwt   = av16 + (size_t)4096 * 1024;             // 3072*2048
  _Float16* wrt   = wwt  + (size_t)3072 * 2048;             // 1024*2048
  _Float16* wot   = wrt  + (size_t)1024 * 2048;             // 1024*2048
  float*    cdelta = (float*)(wot + (size_t)1024 * 2048);   // 16*2048 f32

  // 0) input conversions / weight splits
  convert_a16<<<8192, 256, 0, stream>>>(mems, inputs, 1, a16);
  convert_a16<<<2048, 256, 0, stream>>>(pos_emb, nullptr, 0, pe16);
  split_w<<<dim3(48, 16), 256, 0, stream>>>(W_w, wwt, 3072);
  split_w<<<dim3(16, 16), 256, 0, stream>>>(W_r, wrt, 1024);
  split_w<<<dim3(16, 16), 256, 0, stream>>>(W_o, wot, 1024);
  // 1) qkv = cat @ W_w, fused scatter to qw16/k16/vt16
  gemm2<<<dim3(24, 64), 256, 0, stream>>>(a16, wwt, 0, rwb, qw16, k16, vt16, nullptr);
  // 2) r16 = pos_emb @ W_r
  gemm2<<<dim3(8, 16), 256, 0, stream>>>(pe16, wrt, 1, rwb, r16, nullptr, nullptr, nullptr);
  // 3) cdelta
  cdelta_kernel<<<128, 256, 0, stream>>>(r16, rwb, rrb, cdelta);
  // 4) MFMA flash attention (writes fp16 av16)
  attn_mfma2<<<dim3(8, 16, 4), 256, 0, stream>>>(qw16, k16, vt16, r16, cdelta, av16);
  // 5) out = av16 @ W_o (fp32 out)
  gemm2<<<dim3(8, 32), 256, 0, stream>>>(av16, wot, 2, rwb, nullptr, nullptr, nullptr, out);
}

// Round 6
// 441.544 us; speedup vs baseline: 6.9225x; 1.0483x over previous
//
#include <hip/hip_runtime.h>
#include <cstdint>
#include <cstddef>

static constexpr int QL = 1024;   // q_len
// k_len = 2048, d_model = 1024, heads = 16, depth = 64

typedef _Float16 half8 __attribute__((ext_vector_type(8)));
typedef _Float16 half4 __attribute__((ext_vector_type(4)));
typedef float f32x4 __attribute__((ext_vector_type(4)));

// ---------------------------------------------------------------------------
// gather: A rows come from cat(mems, inputs) per batch (2048 rows/batch)
// ---------------------------------------------------------------------------
__device__ __forceinline__ const float* gemm_row_ptr(const float* A, const float* A2,
                                                     int r, int gather) {
  if (!gather) return A + (size_t)r * 1024;
  int b = r >> 11, tt = r & 2047;
  if (tt < QL) return A + ((size_t)b * QL + tt) * 1024;    // mems part
  return A2 + ((size_t)b * QL + (tt - QL)) * 1024;         // inputs part
}

// ---------------------------------------------------------------------------
// fp32 -> fp16 row conversion (optionally gathered from cat(mems,inputs))
// ---------------------------------------------------------------------------
__global__ __launch_bounds__(256) void convert_a16(
    const float* __restrict__ A, const float* __restrict__ A2, int gather,
    _Float16* __restrict__ dst) {
  const int row = blockIdx.x;
  const int c = threadIdx.x * 4;
  const float* src = gemm_row_ptr(A, A2, row, gather);
  float4 v = *(const float4*)(src + c);
  half4 o = { (_Float16)v.x, (_Float16)v.y, (_Float16)v.z, (_Float16)v.w };
  *(half4*)(dst + (size_t)row * 1024 + c) = o;
}

// ---------------------------------------------------------------------------
// Pre-pass: W[1024][N] -> Wt[N][2048] fp16, rows = [k-tile: hi32|lo32][...]
// ---------------------------------------------------------------------------
__global__ __launch_bounds__(256) void split_w(
    const float* __restrict__ W, _Float16* __restrict__ Wt, int N) {
  __shared__ float T[64][65];
  const int nb = blockIdx.x * 64, kb = blockIdx.y * 64;
  const int t = threadIdx.x;
  {
    int row = t >> 2, c0 = (t & 3) * 16;
    const float* src = W + (size_t)(kb + row) * N + nb + c0;
#pragma unroll
    for (int c = 0; c < 16; c += 4) {
      float4 v = *(const float4*)(src + c);
      T[row][c0 + c + 0] = v.x; T[row][c0 + c + 1] = v.y;
      T[row][c0 + c + 2] = v.z; T[row][c0 + c + 3] = v.w;
    }
  }
  __syncthreads();
  {
    int nrow = t >> 2, ks = (t & 3) * 16;
    half8 hi0, hi1, lo0, lo1;
#pragma unroll
    for (int c = 0; c < 16; ++c) {
      float f = T[ks + c][nrow];
      _Float16 h = (_Float16)f;
      _Float16 l = (_Float16)(f - (float)h);
      if (c < 8) { hi0[c] = h; lo0[c] = l; } else { hi1[c - 8] = h; lo1[c - 8] = l; }
    }
    int kglob = kb + ks;
    int kt = kglob >> 5, pos = kglob & 31;
    _Float16* dst = Wt + (size_t)(nb + nrow) * 2048 + kt * 64 + pos;
    *(half8*)dst = hi0; *(half8*)(dst + 8) = hi1;
    *(half8*)(dst + 32) = lo0; *(half8*)(dst + 40) = lo1;
  }
}

// ---------------------------------------------------------------------------
// 2-term split GEMM: C = A16 @ W  ~=  A@Whi + A@Wlo   (A already fp16)
// 128x128 tile, BK=32, 4 waves x (64x64). Fused mode-specific epilogues:
//   mode 0: qkv -> qw16 (+r_w_bias) / k16 / vt16 (transposed), N=3072
//   mode 1: r   -> r16 [h][jr][d], N=1024
//   mode 2: out -> fp32 C, N=1024
// ---------------------------------------------------------------------------
__global__ __launch_bounds__(256) void gemm2(
    const _Float16* __restrict__ A16, const _Float16* __restrict__ Bt,
    int mode, const float* __restrict__ rwb,
    _Float16* __restrict__ d_q, _Float16* __restrict__ d_k,
    _Float16* __restrict__ d_v, float* __restrict__ d_f) {
  const int nbase = blockIdx.x * 128, mbase = blockIdx.y * 128;
  if (mode == 0 && nbase < 1024 && (mbase & 1024) == 0) return;

  __shared__ __align__(16) _Float16 As[128][40];
  __shared__ __align__(16) _Float16 Bs[128][72];
  const int t = threadIdx.x;
  const int lane = t & 63, w = t >> 6;
  const int ln = lane & 15, g = lane >> 4;
  const int wm = (w & 1) * 64, wn = (w >> 1) * 64;
  const int ar = t >> 1, aseg = (t & 1) * 16;
  const int br = t >> 1, bseg = (t & 1) * 32;
  const _Float16* arow = A16 + (size_t)(mbase + ar) * 1024 + aseg;
  const _Float16* brow = Bt + (size_t)(nbase + br) * 2048 + bseg;

  f32x4 acc[4][4] = {};
  for (int kt = 0; kt < 32; ++kt) {
    half8 a0 = *(const half8*)(arow + kt * 32);
    half8 a1 = *(const half8*)(arow + kt * 32 + 8);
    half8 b0 = *(const half8*)(brow + kt * 64 + 0);
    half8 b1 = *(const half8*)(brow + kt * 64 + 8);
    half8 b2 = *(const half8*)(brow + kt * 64 + 16);
    half8 b3 = *(const half8*)(brow + kt * 64 + 24);
    __syncthreads();
    *(half8*)&As[ar][aseg] = a0;      *(half8*)&As[ar][aseg + 8] = a1;
    *(half8*)&Bs[br][bseg + 0] = b0;  *(half8*)&Bs[br][bseg + 8] = b1;
    *(half8*)&Bs[br][bseg + 16] = b2; *(half8*)&Bs[br][bseg + 24] = b3;
    __syncthreads();
    half8 ah[4], bh[4], bl[4];
#pragma unroll
    for (int i = 0; i < 4; ++i)
      ah[i] = *(const half8*)&As[wm + i * 16 + ln][g * 8];
#pragma unroll
    for (int j = 0; j < 4; ++j) {
      bh[j] = *(const half8*)&Bs[wn + j * 16 + ln][g * 8];
      bl[j] = *(const half8*)&Bs[wn + j * 16 + ln][32 + g * 8];
    }
#pragma unroll
    for (int i = 0; i < 4; ++i)
#pragma unroll
      for (int j = 0; j < 4; ++j) {
        acc[i][j] = __builtin_amdgcn_mfma_f32_16x16x32_f16(ah[i], bh[j], acc[i][j], 0, 0, 0);
        acc[i][j] = __builtin_amdgcn_mfma_f32_16x16x32_f16(ah[i], bl[j], acc[i][j], 0, 0, 0);
      }
  }

  if (mode == 2) {
#pragma unroll
    for (int i = 0; i < 4; ++i)
#pragma unroll
      for (int j = 0; j < 4; ++j) {
        float* cp = d_f + (size_t)(mbase + wm + i * 16 + g * 4) * 1024 + nbase + wn + j * 16 + ln;
#pragma unroll
        for (int r = 0; r < 4; ++r) cp[(size_t)r * 1024] = acc[i][j][r];
      }
    return;
  }
  if (mode == 1) {
#pragma unroll
    for (int j = 0; j < 4; ++j) {
      int n = nbase + wn + j * 16 + ln;
      int h = n >> 6, d = n & 63;
#pragma unroll
      for (int i = 0; i < 4; ++i) {
        int m0 = mbase + wm + i * 16 + g * 4;
        _Float16* rp = d_q + ((size_t)h * 2048 + m0) * 64 + d;   // d_q = r16
#pragma unroll
        for (int r = 0; r < 4; ++r) rp[(size_t)r * 64] = (_Float16)acc[i][j][r];
      }
    }
    return;
  }
  // mode 0: qkv fused scatter
#pragma unroll
  for (int j = 0; j < 4; ++j) {
    int n = nbase + wn + j * 16 + ln;
    int sec = n >> 10;              // 0=q 1=k 2=v
    int c2 = n & 1023, h = c2 >> 6, d = c2 & 63;
    float bias = (sec == 0) ? rwb[c2] : 0.f;
#pragma unroll
    for (int i = 0; i < 4; ++i) {
      int m0 = mbase + wm + i * 16 + g * 4;
      int b = m0 >> 11, tt0 = m0 & 2047;
      size_t bh = (size_t)(b * 16 + h);
#pragma unroll
      for (int r = 0; r < 4; ++r) {
        int tt = tt0 + r;
        float v = acc[i][j][r];
        if (sec == 0) {
          if (tt >= 1024)
            d_q[(bh * 1024 + (tt - 1024)) * 64 + d] = (_Float16)(v + bias);
        } else if (sec == 1) {
          d_k[(bh * 2048 + tt) * 64 + d] = (_Float16)v;
        } else {
          d_v[(bh * 64 + d) * 2048 + tt] = (_Float16)v;
        }
      }
    }
  }
}

// ---------------------------------------------------------------------------
// cdelta[h][jr] = sum_d (r_r_bias - r_w_bias)[h][d] * r16[h][jr][d]
// ---------------------------------------------------------------------------
__global__ __launch_bounds__(256) void cdelta_kernel(
    const _Float16* __restrict__ r16, const float* __restrict__ rwb,
    const float* __restrict__ rrb, float* __restrict__ cd) {
  int idx = blockIdx.x * 256 + threadIdx.x;
  int jr = idx >> 4, h = idx & 15;
  const _Float16* rp = r16 + ((size_t)h * 2048 + jr) * 64;
  const float* a = rrb + h * 64;
  const float* b = rwb + h * 64;
  float s = 0.f;
#pragma unroll 8
  for (int d = 0; d < 64; ++d) s += (a[d] - b[d]) * (float)rp[d];
  cd[h * 2048 + jr] = s;
}

// ---------------------------------------------------------------------------
// MFMA flash attention v3:
//  - no online max (scores bounded; exp(s) direct) -> no shfl chains in loop
//  - scratch stride 21 (2-way max conflicts), scalar writes
//  - r ring buffer: only 64 new rows staged per k-tile
//  - XCD swizzle: id = pr*64 + (h*4+b) so pr-blocks sharing K/V/r co-locate
// ---------------------------------------------------------------------------
__global__ __launch_bounds__(256) void attn_mfma3(
    const _Float16* __restrict__ qw16, const _Float16* __restrict__ k16,
    const _Float16* __restrict__ vt16, const _Float16* __restrict__ r16,
    const float* __restrict__ cdelta, _Float16* __restrict__ av16) {
  __shared__ __align__(16) float scratch[4][80][21];  // [wave][win col][q row]; qw_s overlaid
  __shared__ __align__(16) _Float16 k_s[64][72];
  __shared__ __align__(16) _Float16 vt_s[64][72];
  __shared__ __align__(16) _Float16 r_s[128][72];     // ring, 2 halves of 64 rows
  __shared__ __align__(16) _Float16 P_s[4][16][72];
  __shared__ float cdw_s[128];                         // ring, same slots as r_s
  _Float16 (*qw_s)[72] = (_Float16 (*)[72])&scratch[0][0][0];

  const int id = blockIdx.x;
  const int hb = id & 63, pr = id >> 6;
  const int h = hb >> 2, b = hb & 3;
  const int bh = b * 16 + h;
  const int t = threadIdx.x;
  const int lane = t & 63, w = t >> 6;
  const int ln = lane & 15, g = lane >> 4;
  const int rb = 48 - 16 * w;          // wave window base within the 128-pos window

  const int s_row4 = t >> 2, s_c16 = (t & 3) * 16;
  const int s_row2 = t >> 1, s_c32 = (t & 1) * 32;

  const float* cdh = cdelta + h * 2048;
  const _Float16* kb_p = k16 + (size_t)bh * 2048 * 64;
  const _Float16* vb_p = vt16 + (size_t)bh * 64 * 2048;
  const _Float16* rb_p = r16 + (size_t)h * 2048 * 64;
  const _Float16* qb_p = qw16 + (size_t)bh * 1024 * 64;

#pragma unroll 1
  for (int phase = 0; phase < 2; ++phase) {
    const int qt = phase ? (15 - pr) : pr;
    const int qbase = qt * 64;
    const int ktiles = qt + 17;
    const int R0 = 960 - qbase;        // global r row of window pos 0 at kt=0 (>=0)

    __syncthreads();
    {
      const _Float16* src = qb_p + (size_t)(qbase + s_row4) * 64 + s_c16;
      half8 a0 = *(const half8*)src;
      half8 a1 = *(const half8*)(src + 8);
      *(half8*)&qw_s[s_row4][s_c16] = a0;
      *(half8*)&qw_s[s_row4][s_c16 + 8] = a1;
    }
    __syncthreads();
    half8 aq0 = *(const half8*)&qw_s[16 * w + ln][g * 8];
    half8 aq1 = *(const half8*)&qw_s[16 * w + ln][32 + g * 8];
    __syncthreads();

    f32x4 O[4] = {};
    float llane[4] = {0.f, 0.f, 0.f, 0.f};

    // prefetch tile 0 (K/V 64 rows; r full 128-row window; cd window)
    half8 kp0, kp1, vp0, vp1, rp0, rp1, rp2, rp3;
    float cdp = 0.f;
    {
      const _Float16* kp = kb_p + (size_t)s_row4 * 64 + s_c16;
      kp0 = *(const half8*)kp; kp1 = *(const half8*)(kp + 8);
      const _Float16* vp = vb_p + (size_t)s_row4 * 2048 + s_c16;
      vp0 = *(const half8*)vp; vp1 = *(const half8*)(vp + 8);
      int rr = R0 + s_row2; rr = rr > 2047 ? 2047 : rr;
      const _Float16* rp = rb_p + (size_t)rr * 64 + s_c32;
      rp0 = *(const half8*)rp;        rp1 = *(const half8*)(rp + 8);
      rp2 = *(const half8*)(rp + 16); rp3 = *(const half8*)(rp + 24);
      if (t < 128) { int cr = R0 + t; cr = cr > 2047 ? 2047 : cr; cdp = cdh[cr]; }
    }

    for (int kt = 0; kt < ktiles; ++kt) {
      const int kbase = kt * 64;
      const int koff = (kt & 1) * 64;  // ring offset for window pos 0
      __syncthreads();
      *(half8*)&k_s[s_row4][s_c16] = kp0;  *(half8*)&k_s[s_row4][s_c16 + 8] = kp1;
      *(half8*)&vt_s[s_row4][s_c16] = vp0; *(half8*)&vt_s[s_row4][s_c16 + 8] = vp1;
      if (kt == 0) {
        *(half8*)&r_s[s_row2][s_c32] = rp0;      *(half8*)&r_s[s_row2][s_c32 + 8] = rp1;
        *(half8*)&r_s[s_row2][s_c32 + 16] = rp2; *(half8*)&r_s[s_row2][s_c32 + 24] = rp3;
        if (t < 128) cdw_s[t] = cdp;
      } else {
        const int sb = 64 - koff;      // this tile's new-rows slot base
        *(half8*)&r_s[sb + s_row4][s_c16] = rp0;
        *(half8*)&r_s[sb + s_row4][s_c16 + 8] = rp1;
        if (t < 64) cdw_s[sb + t] = cdp;
      }
      __syncthreads();
      if (kt + 1 < ktiles) {           // prefetch next tile during compute
        const int kb2 = kbase + 64;
        const _Float16* kp = kb_p + (size_t)(kb2 + s_row4) * 64 + s_c16;
        kp0 = *(const half8*)kp; kp1 = *(const half8*)(kp + 8);
        const _Float16* vp = vb_p + (size_t)s_row4 * 2048 + kb2 + s_c16;
        vp0 = *(const half8*)vp; vp1 = *(const half8*)(vp + 8);
        int rr = R0 + kbase + 128 + s_row4; rr = rr > 2047 ? 2047 : rr;
        const _Float16* rp = rb_p + (size_t)rr * 64 + s_c16;
        rp0 = *(const half8*)rp; rp1 = *(const half8*)(rp + 8);
        if (t < 64) { int cr = R0 + kbase + 128 + t; cr = cr > 2047 ? 2047 : cr; cdp = cdh[cr]; }
      }

      // ---- QK^T: 4 j-tiles ----
      f32x4 Sf[4];
#pragma unroll
      for (int jt = 0; jt < 4; ++jt) {
        half8 b0 = *(const half8*)&k_s[jt * 16 + ln][g * 8];
        half8 b1 = *(const half8*)&k_s[jt * 16 + ln][32 + g * 8];
        f32x4 z = {0.f, 0.f, 0.f, 0.f};
        z = __builtin_amdgcn_mfma_f32_16x16x32_f16(aq0, b0, z, 0, 0, 0);
        z = __builtin_amdgcn_mfma_f32_16x16x32_f16(aq1, b1, z, 0, 0, 0);
        Sf[jt] = z;
      }
      // ---- T window (5 col-tiles of 16) + cdelta fold, into per-wave scratch ----
#pragma unroll
      for (int ft = 0; ft < 5; ++ft) {
        int rrow = (rb + ft * 16 + ln + koff) & 127;
        half8 b0 = *(const half8*)&r_s[rrow][g * 8];
        half8 b1 = *(const half8*)&r_s[rrow][32 + g * 8];
        f32x4 z = {0.f, 0.f, 0.f, 0.f};
        z = __builtin_amdgcn_mfma_f32_16x16x32_f16(aq0, b0, z, 0, 0, 0);
        z = __builtin_amdgcn_mfma_f32_16x16x32_f16(aq1, b1, z, 0, 0, 0);
        float cdv = cdw_s[rrow];
        float* sc = &scratch[w][ft * 16 + ln][0];
        sc[4 * g + 0] = z[0] + cdv; sc[4 * g + 1] = z[1] + cdv;
        sc[4 * g + 2] = z[2] + cdv; sc[4 * g + 3] = z[3] + cdv;
      }
      // ---- scores -> p = exp(s) (no max subtraction; s bounded), P_s, l ----
      const int climit = qbase + 16 * w + 1039 - kbase;
#pragma unroll
      for (int r = 0; r < 4; ++r) {
        float psum = 0.f;
#pragma unroll
        for (int jt = 0; jt < 4; ++jt) {
          int cw = jt * 16 + ln + 15 - 4 * g - r;
          float tv = scratch[w][cw][4 * g + r];
          float x = (Sf[jt][r] + tv) * 0.125f;
          float p = (cw > climit) ? 0.f : __expf(x);
          psum += p;
          P_s[w][4 * g + r][jt * 16 + ln] = (_Float16)p;
        }
        llane[r] += psum;
      }
      // ---- PV ----
      half8 pA0 = *(const half8*)&P_s[w][ln][g * 8];
      half8 pA1 = *(const half8*)&P_s[w][ln][32 + g * 8];
#pragma unroll
      for (int dt = 0; dt < 4; ++dt) {
        half8 b0 = *(const half8*)&vt_s[dt * 16 + ln][g * 8];
        half8 b1 = *(const half8*)&vt_s[dt * 16 + ln][32 + g * 8];
        O[dt] = __builtin_amdgcn_mfma_f32_16x16x32_f16(pA0, b0, O[dt], 0, 0, 0);
        O[dt] = __builtin_amdgcn_mfma_f32_16x16x32_f16(pA1, b1, O[dt], 0, 0, 0);
      }
    }

    // ---- epilogue: reduce l across the 16-lane row group, normalize, store ----
#pragma unroll
    for (int r = 0; r < 4; ++r) {
      float ls = llane[r];
      ls += __shfl_xor(ls, 1, 64);
      ls += __shfl_xor(ls, 2, 64);
      ls += __shfl_xor(ls, 4, 64);
      ls += __shfl_xor(ls, 8, 64);
      float inv = 1.f / ls;
      int qrow = qbase + 16 * w + 4 * g + r;
      _Float16* op = av16 + ((size_t)b * 1024 + qrow) * 1024 + h * 64 + ln;
#pragma unroll
      for (int dt = 0; dt < 4; ++dt) op[dt * 16] = (_Float16)(O[dt][r] * inv);
    }
  }
}

// ---------------------------------------------------------------------------
extern "C" void kernel_launch(void* const* d_in, const int* in_sizes, int n_in,
                              void* d_out, int out_size, void* d_ws, size_t ws_size,
                              hipStream_t stream) {
  const float* inputs  = (const float*)d_in[0];
  const float* pos_emb = (const float*)d_in[1];
  const float* rwb     = (const float*)d_in[2];
  const float* rrb     = (const float*)d_in[3];
  const float* mems    = (const float*)d_in[4];
  const float* W_w     = (const float*)d_in[5];
  const float* W_r     = (const float*)d_in[6];
  const float* W_o     = (const float*)d_in[7];
  float* out = (float*)d_out;

  _Float16* hws = (_Float16*)d_ws;
  _Float16* a16   = hws;                                    // 8192*1024
  _Float16* pe16  = a16  + (size_t)8192 * 1024;             // 2048*1024
  _Float16* qw16  = pe16 + (size_t)2048 * 1024;             // 64*1024*64
  _Float16* k16   = qw16 + (size_t)64 * 1024 * 64;          // 64*2048*64
  _Float16* vt16  = k16  + (size_t)64 * 2048 * 64;          // 64*64*2048
  _Float16* r16   = vt16 + (size_t)64 * 64 * 2048;          // 16*2048*64
  _Float16* av16  = r16  + (size_t)16 * 2048 * 64;          // 4096*1024
  _Float16* wwt   = av16 + (size_t)4096 * 1024;             // 3072*2048
  _Float16* wrt   = wwt  + (size_t)3072 * 2048;             // 1024*2048
  _Float16* wot   = wrt  + (size_t)1024 * 2048;             // 1024*2048
  float*    cdelta = (float*)(wot + (size_t)1024 * 2048);   // 16*2048 f32

  // 0) input conversions / weight splits
  convert_a16<<<8192, 256, 0, stream>>>(mems, inputs, 1, a16);
  convert_a16<<<2048, 256, 0, stream>>>(pos_emb, nullptr, 0, pe16);
  split_w<<<dim3(48, 16), 256, 0, stream>>>(W_w, wwt, 3072);
  split_w<<<dim3(16, 16), 256, 0, stream>>>(W_r, wrt, 1024);
  split_w<<<dim3(16, 16), 256, 0, stream>>>(W_o, wot, 1024);
  // 1) qkv = cat @ W_w, fused scatter to qw16/k16/vt16
  gemm2<<<dim3(24, 64), 256, 0, stream>>>(a16, wwt, 0, rwb, qw16, k16, vt16, nullptr);
  // 2) r16 = pos_emb @ W_r
  gemm2<<<dim3(8, 16), 256, 0, stream>>>(pe16, wrt, 1, rwb, r16, nullptr, nullptr, nullptr);
  // 3) cdelta
  cdelta_kernel<<<128, 256, 0, stream>>>(r16, rwb, rrb, cdelta);
  // 4) MFMA flash attention v3 (XCD-swizzled 1D grid)
  attn_mfma3<<<512, 256, 0, stream>>>(qw16, k16, vt16, r16, cdelta, av16);
  // 5) out = av16 @ W_o (fp32 out)
  gemm2<<<dim3(8, 32), 256, 0, stream>>>(av16, wot, 2, rwb, nullptr, nullptr, nullptr, out);
}

// Round 7
// 382.765 us; speedup vs baseline: 7.9856x; 1.1536x over previous
//
#include <hip/hip_runtime.h>
#include <cstdint>
#include <cstddef>

static constexpr int QL = 1024;   // q_len
// k_len = 2048, d_model = 1024, heads = 16, depth = 64

typedef _Float16 half8 __attribute__((ext_vector_type(8)));
typedef _Float16 half4 __attribute__((ext_vector_type(4)));
typedef float f32x4 __attribute__((ext_vector_type(4)));

// ---------------------------------------------------------------------------
// gather: A rows come from cat(mems, inputs) per batch (2048 rows/batch)
// ---------------------------------------------------------------------------
__device__ __forceinline__ const float* gemm_row_ptr(const float* A, const float* A2,
                                                     int r, int gather) {
  if (!gather) return A + (size_t)r * 1024;
  int b = r >> 11, tt = r & 2047;
  if (tt < QL) return A + ((size_t)b * QL + tt) * 1024;    // mems part
  return A2 + ((size_t)b * QL + (tt - QL)) * 1024;         // inputs part
}

// ---------------------------------------------------------------------------
// fp32 -> fp16 row conversion (optionally gathered from cat(mems,inputs))
// ---------------------------------------------------------------------------
__global__ __launch_bounds__(256) void convert_a16(
    const float* __restrict__ A, const float* __restrict__ A2, int gather,
    _Float16* __restrict__ dst) {
  const int row = blockIdx.x;
  const int c = threadIdx.x * 4;
  const float* src = gemm_row_ptr(A, A2, row, gather);
  float4 v = *(const float4*)(src + c);
  half4 o = { (_Float16)v.x, (_Float16)v.y, (_Float16)v.z, (_Float16)v.w };
  *(half4*)(dst + (size_t)row * 1024 + c) = o;
}

// ---------------------------------------------------------------------------
// Pre-pass: W[1024][N] -> Wt[N][2048] fp16, rows = [k-tile: hi32|lo32][...]
// (modes 0/1 read only the hi halves; mode 2 reads both)
// ---------------------------------------------------------------------------
__global__ __launch_bounds__(256) void split_w(
    const float* __restrict__ W, _Float16* __restrict__ Wt, int N) {
  __shared__ float T[64][65];
  const int nb = blockIdx.x * 64, kb = blockIdx.y * 64;
  const int t = threadIdx.x;
  {
    int row = t >> 2, c0 = (t & 3) * 16;
    const float* src = W + (size_t)(kb + row) * N + nb + c0;
#pragma unroll
    for (int c = 0; c < 16; c += 4) {
      float4 v = *(const float4*)(src + c);
      T[row][c0 + c + 0] = v.x; T[row][c0 + c + 1] = v.y;
      T[row][c0 + c + 2] = v.z; T[row][c0 + c + 3] = v.w;
    }
  }
  __syncthreads();
  {
    int nrow = t >> 2, ks = (t & 3) * 16;
    half8 hi0, hi1, lo0, lo1;
#pragma unroll
    for (int c = 0; c < 16; ++c) {
      float f = T[ks + c][nrow];
      _Float16 h = (_Float16)f;
      _Float16 l = (_Float16)(f - (float)h);
      if (c < 8) { hi0[c] = h; lo0[c] = l; } else { hi1[c - 8] = h; lo1[c - 8] = l; }
    }
    int kglob = kb + ks;
    int kt = kglob >> 5, pos = kglob & 31;
    _Float16* dst = Wt + (size_t)(nb + nrow) * 2048 + kt * 64 + pos;
    *(half8*)dst = hi0; *(half8*)(dst + 8) = hi1;
    *(half8*)(dst + 32) = lo0; *(half8*)(dst + 40) = lo1;
  }
}

// ---------------------------------------------------------------------------
// MFMA GEMM with register prefetch. modes 0/1: 1-term fp16 (A@Whi; outputs are
// re-rounded to fp16 anyway so the lo term is below the store's own noise).
// mode 2: 2-term (A@Whi + A@Wlo), fp32 output.
// 128x128 tile, BK=32, 4 waves x (64x64). Fused epilogues:
//   mode 0: qkv -> qw16 (+r_w_bias) / k16 / vt16 (transposed), N=3072
//   mode 1: r   -> r16 [h][jr][d], N=1024
//   mode 2: out -> fp32 C, N=1024
// ---------------------------------------------------------------------------
__global__ __launch_bounds__(256) void gemm2(
    const _Float16* __restrict__ A16, const _Float16* __restrict__ Bt,
    int mode, const float* __restrict__ rwb,
    _Float16* __restrict__ d_q, _Float16* __restrict__ d_k,
    _Float16* __restrict__ d_v, float* __restrict__ d_f) {
  const int nbase = blockIdx.x * 128, mbase = blockIdx.y * 128;
  if (mode == 0 && nbase < 1024 && (mbase & 1024) == 0) return;

  __shared__ __align__(16) _Float16 As[128][40];
  __shared__ __align__(16) _Float16 Bs[128][72];
  const int t = threadIdx.x;
  const int lane = t & 63, w = t >> 6;
  const int ln = lane & 15, g = lane >> 4;
  const int wm = (w & 1) * 64, wn = (w >> 1) * 64;
  const int ar = t >> 1, aseg = (t & 1) * 16;
  const int br = t >> 1;
  const int bseg = (mode == 2) ? (t & 1) * 32 : (t & 1) * 16;
  const _Float16* arow = A16 + (size_t)(mbase + ar) * 1024 + aseg;
  const _Float16* brow = Bt + (size_t)(nbase + br) * 2048 + bseg;

  // prefetch k-tile 0
  half8 pa0, pa1, pb0, pb1, pb2, pb3;
  pa0 = *(const half8*)(arow);      pa1 = *(const half8*)(arow + 8);
  pb0 = *(const half8*)(brow);      pb1 = *(const half8*)(brow + 8);
  if (mode == 2) { pb2 = *(const half8*)(brow + 16); pb3 = *(const half8*)(brow + 24); }

  f32x4 acc[4][4] = {};
  for (int kt = 0; kt < 32; ++kt) {
    __syncthreads();
    *(half8*)&As[ar][aseg] = pa0;     *(half8*)&As[ar][aseg + 8] = pa1;
    *(half8*)&Bs[br][bseg] = pb0;     *(half8*)&Bs[br][bseg + 8] = pb1;
    if (mode == 2) { *(half8*)&Bs[br][bseg + 16] = pb2; *(half8*)&Bs[br][bseg + 24] = pb3; }
    __syncthreads();
    if (kt + 1 < 32) {   // prefetch next tile; latency hides under MFMAs
      const _Float16* ap = arow + (kt + 1) * 32;
      const _Float16* bp = brow + (kt + 1) * 64;
      pa0 = *(const half8*)(ap);      pa1 = *(const half8*)(ap + 8);
      pb0 = *(const half8*)(bp);      pb1 = *(const half8*)(bp + 8);
      if (mode == 2) { pb2 = *(const half8*)(bp + 16); pb3 = *(const half8*)(bp + 24); }
    }
    half8 ah[4], bh[4], bl[4];
#pragma unroll
    for (int i = 0; i < 4; ++i)
      ah[i] = *(const half8*)&As[wm + i * 16 + ln][g * 8];
#pragma unroll
    for (int j = 0; j < 4; ++j)
      bh[j] = *(const half8*)&Bs[wn + j * 16 + ln][g * 8];
    if (mode == 2) {
#pragma unroll
      for (int j = 0; j < 4; ++j)
        bl[j] = *(const half8*)&Bs[wn + j * 16 + ln][32 + g * 8];
    }
#pragma unroll
    for (int i = 0; i < 4; ++i)
#pragma unroll
      for (int j = 0; j < 4; ++j) {
        acc[i][j] = __builtin_amdgcn_mfma_f32_16x16x32_f16(ah[i], bh[j], acc[i][j], 0, 0, 0);
        if (mode == 2)
          acc[i][j] = __builtin_amdgcn_mfma_f32_16x16x32_f16(ah[i], bl[j], acc[i][j], 0, 0, 0);
      }
  }

  if (mode == 2) {
#pragma unroll
    for (int i = 0; i < 4; ++i)
#pragma unroll
      for (int j = 0; j < 4; ++j) {
        float* cp = d_f + (size_t)(mbase + wm + i * 16 + g * 4) * 1024 + nbase + wn + j * 16 + ln;
#pragma unroll
        for (int r = 0; r < 4; ++r) cp[(size_t)r * 1024] = acc[i][j][r];
      }
    return;
  }
  if (mode == 1) {
#pragma unroll
    for (int j = 0; j < 4; ++j) {
      int n = nbase + wn + j * 16 + ln;
      int h = n >> 6, d = n & 63;
#pragma unroll
      for (int i = 0; i < 4; ++i) {
        int m0 = mbase + wm + i * 16 + g * 4;
        _Float16* rp = d_q + ((size_t)h * 2048 + m0) * 64 + d;   // d_q = r16
#pragma unroll
        for (int r = 0; r < 4; ++r) rp[(size_t)r * 64] = (_Float16)acc[i][j][r];
      }
    }
    return;
  }
  // mode 0: qkv fused scatter
#pragma unroll
  for (int j = 0; j < 4; ++j) {
    int n = nbase + wn + j * 16 + ln;
    int sec = n >> 10;              // 0=q 1=k 2=v
    int c2 = n & 1023, h = c2 >> 6, d = c2 & 63;
    float bias = (sec == 0) ? rwb[c2] : 0.f;
#pragma unroll
    for (int i = 0; i < 4; ++i) {
      int m0 = mbase + wm + i * 16 + g * 4;
      int b = m0 >> 11, tt0 = m0 & 2047;
      size_t bh = (size_t)(b * 16 + h);
#pragma unroll
      for (int r = 0; r < 4; ++r) {
        int tt = tt0 + r;
        float v = acc[i][j][r];
        if (sec == 0) {
          if (tt >= 1024)
            d_q[(bh * 1024 + (tt - 1024)) * 64 + d] = (_Float16)(v + bias);
        } else if (sec == 1) {
          d_k[(bh * 2048 + tt) * 64 + d] = (_Float16)v;
        } else {
          d_v[(bh * 64 + d) * 2048 + tt] = (_Float16)v;
        }
      }
    }
  }
}

// ---------------------------------------------------------------------------
// cdelta[h][jr] = sum_d (r_r_bias - r_w_bias)[h][d] * r16[h][jr][d]
// ---------------------------------------------------------------------------
__global__ __launch_bounds__(256) void cdelta_kernel(
    const _Float16* __restrict__ r16, const float* __restrict__ rwb,
    const float* __restrict__ rrb, float* __restrict__ cd) {
  int idx = blockIdx.x * 256 + threadIdx.x;
  int jr = idx >> 4, h = idx & 15;
  const _Float16* rp = r16 + ((size_t)h * 2048 + jr) * 64;
  const float* a = rrb + h * 64;
  const float* b = rwb + h * 64;
  float s = 0.f;
#pragma unroll 8
  for (int d = 0; d < 64; ++d) s += (a[d] - b[d]) * (float)rp[d];
  cd[h * 2048 + jr] = s;
}

// ---------------------------------------------------------------------------
// MFMA flash attention v3 (unchanged from R6).
// ---------------------------------------------------------------------------
__global__ __launch_bounds__(256) void attn_mfma3(
    const _Float16* __restrict__ qw16, const _Float16* __restrict__ k16,
    const _Float16* __restrict__ vt16, const _Float16* __restrict__ r16,
    const float* __restrict__ cdelta, _Float16* __restrict__ av16) {
  __shared__ __align__(16) float scratch[4][80][21];  // [wave][win col][q row]; qw_s overlaid
  __shared__ __align__(16) _Float16 k_s[64][72];
  __shared__ __align__(16) _Float16 vt_s[64][72];
  __shared__ __align__(16) _Float16 r_s[128][72];     // ring, 2 halves of 64 rows
  __shared__ __align__(16) _Float16 P_s[4][16][72];
  __shared__ float cdw_s[128];                         // ring, same slots as r_s
  _Float16 (*qw_s)[72] = (_Float16 (*)[72])&scratch[0][0][0];

  const int id = blockIdx.x;
  const int hb = id & 63, pr = id >> 6;
  const int h = hb >> 2, b = hb & 3;
  const int bh = b * 16 + h;
  const int t = threadIdx.x;
  const int lane = t & 63, w = t >> 6;
  const int ln = lane & 15, g = lane >> 4;
  const int rb = 48 - 16 * w;          // wave window base within the 128-pos window

  const int s_row4 = t >> 2, s_c16 = (t & 3) * 16;
  const int s_row2 = t >> 1, s_c32 = (t & 1) * 32;

  const float* cdh = cdelta + h * 2048;
  const _Float16* kb_p = k16 + (size_t)bh * 2048 * 64;
  const _Float16* vb_p = vt16 + (size_t)bh * 64 * 2048;
  const _Float16* rb_p = r16 + (size_t)h * 2048 * 64;
  const _Float16* qb_p = qw16 + (size_t)bh * 1024 * 64;

#pragma unroll 1
  for (int phase = 0; phase < 2; ++phase) {
    const int qt = phase ? (15 - pr) : pr;
    const int qbase = qt * 64;
    const int ktiles = qt + 17;
    const int R0 = 960 - qbase;        // global r row of window pos 0 at kt=0 (>=0)

    __syncthreads();
    {
      const _Float16* src = qb_p + (size_t)(qbase + s_row4) * 64 + s_c16;
      half8 a0 = *(const half8*)src;
      half8 a1 = *(const half8*)(src + 8);
      *(half8*)&qw_s[s_row4][s_c16] = a0;
      *(half8*)&qw_s[s_row4][s_c16 + 8] = a1;
    }
    __syncthreads();
    half8 aq0 = *(const half8*)&qw_s[16 * w + ln][g * 8];
    half8 aq1 = *(const half8*)&qw_s[16 * w + ln][32 + g * 8];
    __syncthreads();

    f32x4 O[4] = {};
    float llane[4] = {0.f, 0.f, 0.f, 0.f};

    half8 kp0, kp1, vp0, vp1, rp0, rp1, rp2, rp3;
    float cdp = 0.f;
    {
      const _Float16* kp = kb_p + (size_t)s_row4 * 64 + s_c16;
      kp0 = *(const half8*)kp; kp1 = *(const half8*)(kp + 8);
      const _Float16* vp = vb_p + (size_t)s_row4 * 2048 + s_c16;
      vp0 = *(const half8*)vp; vp1 = *(const half8*)(vp + 8);
      int rr = R0 + s_row2; rr = rr > 2047 ? 2047 : rr;
      const _Float16* rp = rb_p + (size_t)rr * 64 + s_c32;
      rp0 = *(const half8*)rp;        rp1 = *(const half8*)(rp + 8);
      rp2 = *(const half8*)(rp + 16); rp3 = *(const half8*)(rp + 24);
      if (t < 128) { int cr = R0 + t; cr = cr > 2047 ? 2047 : cr; cdp = cdh[cr]; }
    }

    for (int kt = 0; kt < ktiles; ++kt) {
      const int kbase = kt * 64;
      const int koff = (kt & 1) * 64;  // ring offset for window pos 0
      __syncthreads();
      *(half8*)&k_s[s_row4][s_c16] = kp0;  *(half8*)&k_s[s_row4][s_c16 + 8] = kp1;
      *(half8*)&vt_s[s_row4][s_c16] = vp0; *(half8*)&vt_s[s_row4][s_c16 + 8] = vp1;
      if (kt == 0) {
        *(half8*)&r_s[s_row2][s_c32] = rp0;      *(half8*)&r_s[s_row2][s_c32 + 8] = rp1;
        *(half8*)&r_s[s_row2][s_c32 + 16] = rp2; *(half8*)&r_s[s_row2][s_c32 + 24] = rp3;
        if (t < 128) cdw_s[t] = cdp;
      } else {
        const int sb = 64 - koff;      // this tile's new-rows slot base
        *(half8*)&r_s[sb + s_row4][s_c16] = rp0;
        *(half8*)&r_s[sb + s_row4][s_c16 + 8] = rp1;
        if (t < 64) cdw_s[sb + t] = cdp;
      }
      __syncthreads();
      if (kt + 1 < ktiles) {           // prefetch next tile during compute
        const int kb2 = kbase + 64;
        const _Float16* kp = kb_p + (size_t)(kb2 + s_row4) * 64 + s_c16;
        kp0 = *(const half8*)kp; kp1 = *(const half8*)(kp + 8);
        const _Float16* vp = vb_p + (size_t)s_row4 * 2048 + kb2 + s_c16;
        vp0 = *(const half8*)vp; vp1 = *(const half8*)(vp + 8);
        int rr = R0 + kbase + 128 + s_row4; rr = rr > 2047 ? 2047 : rr;
        const _Float16* rp = rb_p + (size_t)rr * 64 + s_c16;
        rp0 = *(const half8*)rp; rp1 = *(const half8*)(rp + 8);
        if (t < 64) { int cr = R0 + kbase + 128 + t; cr = cr > 2047 ? 2047 : cr; cdp = cdh[cr]; }
      }

      // ---- QK^T: 4 j-tiles ----
      f32x4 Sf[4];
#pragma unroll
      for (int jt = 0; jt < 4; ++jt) {
        half8 b0 = *(const half8*)&k_s[jt * 16 + ln][g * 8];
        half8 b1 = *(const half8*)&k_s[jt * 16 + ln][32 + g * 8];
        f32x4 z = {0.f, 0.f, 0.f, 0.f};
        z = __builtin_amdgcn_mfma_f32_16x16x32_f16(aq0, b0, z, 0, 0, 0);
        z = __builtin_amdgcn_mfma_f32_16x16x32_f16(aq1, b1, z, 0, 0, 0);
        Sf[jt] = z;
      }
      // ---- T window (5 col-tiles of 16) + cdelta fold, into per-wave scratch ----
#pragma unroll
      for (int ft = 0; ft < 5; ++ft) {
        int rrow = (rb + ft * 16 + ln + koff) & 127;
        half8 b0 = *(const half8*)&r_s[rrow][g * 8];
        half8 b1 = *(const half8*)&r_s[rrow][32 + g * 8];
        f32x4 z = {0.f, 0.f, 0.f, 0.f};
        z = __builtin_amdgcn_mfma_f32_16x16x32_f16(aq0, b0, z, 0, 0, 0);
        z = __builtin_amdgcn_mfma_f32_16x16x32_f16(aq1, b1, z, 0, 0, 0);
        float cdv = cdw_s[rrow];
        float* sc = &scratch[w][ft * 16 + ln][0];
        sc[4 * g + 0] = z[0] + cdv; sc[4 * g + 1] = z[1] + cdv;
        sc[4 * g + 2] = z[2] + cdv; sc[4 * g + 3] = z[3] + cdv;
      }
      // ---- scores -> p = exp(s) (no max subtraction; s bounded), P_s, l ----
      const int climit = qbase + 16 * w + 1039 - kbase;
#pragma unroll
      for (int r = 0; r < 4; ++r) {
        float psum = 0.f;
#pragma unroll
        for (int jt = 0; jt < 4; ++jt) {
          int cw = jt * 16 + ln + 15 - 4 * g - r;
          float tv = scratch[w][cw][4 * g + r];
          float x = (Sf[jt][r] + tv) * 0.125f;
          float p = (cw > climit) ? 0.f : __expf(x);
          psum += p;
          P_s[w][4 * g + r][jt * 16 + ln] = (_Float16)p;
        }
        llane[r] += psum;
      }
      // ---- PV ----
      half8 pA0 = *(const half8*)&P_s[w][ln][g * 8];
      half8 pA1 = *(const half8*)&P_s[w][ln][32 + g * 8];
#pragma unroll
      for (int dt = 0; dt < 4; ++dt) {
        half8 b0 = *(const half8*)&vt_s[dt * 16 + ln][g * 8];
        half8 b1 = *(const half8*)&vt_s[dt * 16 + ln][32 + g * 8];
        O[dt] = __builtin_amdgcn_mfma_f32_16x16x32_f16(pA0, b0, O[dt], 0, 0, 0);
        O[dt] = __builtin_amdgcn_mfma_f32_16x16x32_f16(pA1, b1, O[dt], 0, 0, 0);
      }
    }

    // ---- epilogue: reduce l across the 16-lane row group, normalize, store ----
#pragma unroll
    for (int r = 0; r < 4; ++r) {
      float ls = llane[r];
      ls += __shfl_xor(ls, 1, 64);
      ls += __shfl_xor(ls, 2, 64);
      ls += __shfl_xor(ls, 4, 64);
      ls += __shfl_xor(ls, 8, 64);
      float inv = 1.f / ls;
      int qrow = qbase + 16 * w + 4 * g + r;
      _Float16* op = av16 + ((size_t)b * 1024 + qrow) * 1024 + h * 64 + ln;
#pragma unroll
      for (int dt = 0; dt < 4; ++dt) op[dt * 16] = (_Float16)(O[dt][r] * inv);
    }
  }
}

// ---------------------------------------------------------------------------
extern "C" void kernel_launch(void* const* d_in, const int* in_sizes, int n_in,
                              void* d_out, int out_size, void* d_ws, size_t ws_size,
                              hipStream_t stream) {
  const float* inputs  = (const float*)d_in[0];
  const float* pos_emb = (const float*)d_in[1];
  const float* rwb     = (const float*)d_in[2];
  const float* rrb     = (const float*)d_in[3];
  const float* mems    = (const float*)d_in[4];
  const float* W_w     = (const float*)d_in[5];
  const float* W_r     = (const float*)d_in[6];
  const float* W_o     = (const float*)d_in[7];
  float* out = (float*)d_out;

  _Float16* hws = (_Float16*)d_ws;
  _Float16* a16   = hws;                                    // 8192*1024
  _Float16* pe16  = a16  + (size_t)8192 * 1024;             // 2048*1024
  _Float16* qw16  = pe16 + (size_t)2048 * 1024;             // 64*1024*64
  _Float16* k16   = qw16 + (size_t)64 * 1024 * 64;          // 64*2048*64
  _Float16* vt16  = k16  + (size_t)64 * 2048 * 64;          // 64*64*2048
  _Float16* r16   = vt16 + (size_t)64 * 64 * 2048;          // 16*2048*64
  _Float16* av16  = r16  + (size_t)16 * 2048 * 64;          // 4096*1024
  _Float16* wwt   = av16 + (size_t)4096 * 1024;             // 3072*2048
  _Float16* wrt   = wwt  + (size_t)3072 * 2048;             // 1024*2048
  _Float16* wot   = wrt  + (size_t)1024 * 2048;             // 1024*2048
  float*    cdelta = (float*)(wot + (size_t)1024 * 2048);   // 16*2048 f32

  // 0) input conversions / weight splits
  convert_a16<<<8192, 256, 0, stream>>>(mems, inputs, 1, a16);
  convert_a16<<<2048, 256, 0, stream>>>(pos_emb, nullptr, 0, pe16);
  split_w<<<dim3(48, 16), 256, 0, stream>>>(W_w, wwt, 3072);
  split_w<<<dim3(16, 16), 256, 0, stream>>>(W_r, wrt, 1024);
  split_w<<<dim3(16, 16), 256, 0, stream>>>(W_o, wot, 1024);
  // 1) qkv = cat @ W_w (1-term fp16), fused scatter to qw16/k16/vt16
  gemm2<<<dim3(24, 64), 256, 0, stream>>>(a16, wwt, 0, rwb, qw16, k16, vt16, nullptr);
  // 2) r16 = pos_emb @ W_r (1-term fp16)
  gemm2<<<dim3(8, 16), 256, 0, stream>>>(pe16, wrt, 1, rwb, r16, nullptr, nullptr, nullptr);
  // 3) cdelta
  cdelta_kernel<<<128, 256, 0, stream>>>(r16, rwb, rrb, cdelta);
  // 4) MFMA flash attention v3 (XCD-swizzled 1D grid)
  attn_mfma3<<<512, 256, 0, stream>>>(qw16, k16, vt16, r16, cdelta, av16);
  // 5) out = av16 @ W_o (2-term, fp32 out)
  gemm2<<<dim3(8, 32), 256, 0, stream>>>(av16, wot, 2, rwb, nullptr, nullptr, nullptr, out);
}